// Round 5
// baseline (613.170 us; speedup 1.0000x reference)
//
#include <hip/hip_runtime.h>
#include <hip/hip_bf16.h>
#include <math.h>

typedef __hip_bfloat16 bf16;
typedef __attribute__((ext_vector_type(8))) short bf16x8;
typedef __attribute__((ext_vector_type(4))) float f32x4;

#define DEVI __device__ __forceinline__

// ---------- constants ----------
#define C_ 512
#define NH_ 4
#define NTOK 11520          // B*T*H*W
#define NKEY 1680           // 360 local + 960 rolled + 360 pooled
#define NRK 120
#define FFN_ 1960
#define ZROW (NTOK + 256)   // zeroed key row for invalid slots

// ---------- helpers ----------
DEVI float ldf(const bf16* p) { return __bfloat162float(*p); }
DEVI float ldf(const float* p) { return *p; }
DEVI void stw(bf16* p, float v) { *p = __float2bfloat16(v); }
DEVI void stw(float* p, float v) { *p = v; }
DEVI unsigned short f2bs(float f) { bf16 h = __float2bfloat16(f); return *(unsigned short*)&h; }

// dtype-dispatched scalar load: DT=0 bf16, DT=1 f32
template <int DT> DEVI float ldw(const void* p, size_t i) {
  if (DT == 0) return __bfloat162float(((const bf16*)p)[i]);
  else         return ((const float*)p)[i];
}

// async global->LDS, 16B per lane; lptr is wave-uniform base (HW adds lane*16)
DEVI void gload_lds16(const void* g, void* l) {
  __builtin_amdgcn_global_load_lds(
      (const __attribute__((address_space(1))) void*)g,
      (__attribute__((address_space(3))) void*)l, 16, 0, 0);
}

// ---------- K_detect ----------
__global__ void k_detect(const void* __restrict__ g1, int* __restrict__ flag) {
  if (threadIdx.x == 0) {
    const unsigned short* p = (const unsigned short*)g1;
    *flag = (p[0] == 0x3F80u) ? 0 : 1;
  }
}

// ---------- K0: valid-index table ----------
__global__ void k_prep(int* __restrict__ table) {
  if (threadIdx.x == 0) {
    int cnt = 0;
    for (int p = 0; p < 4; p++)
      for (int wi = 0; wi < 5; wi++)
        for (int wj = 0; wj < 9; wj++) {
          bool invalid;
          if (p == 0)      invalid = (wi < 3) && (wj < 5);
          else if (p == 1) invalid = (wi < 3) && (wj >= 4);
          else if (p == 2) invalid = (wi >= 2) && (wj < 5);
          else             invalid = (wi >= 2) && (wj >= 4);
          if (!invalid) table[cnt++] = p * 45 + wi * 9 + wj;
        }
  }
}

// ---------- K0b: per-window key-source table ksrc[32][1680] ----------
// values: token row (<NTOK) for local/rolled, NTOK+pidx for pooled, -1 invalid
__global__ void k_ksrc(const int* __restrict__ vtab, int* __restrict__ ksrc) {
  int idx = blockIdx.x * 256 + threadIdx.x;
  if (idx >= 32 * NKEY) return;
  int w = idx / NKEY, j = idx % NKEY;
  int b = w >> 4, nh = (w >> 2) & 3, nw = w & 3;
  int val;
  if (j < 360) {
    int t = j / 45, pos = j % 45, wi = pos / 9, wj2 = pos % 9;
    val = ((b * 8 + t) * 20 + nh * 5 + wi) * 36 + nw * 9 + wj2;
  } else if (j < 1320) {
    int jj = j - 360;
    int t = jj / 120, r = jj % 120;
    int id = vtab[r];
    int p = id / 45, pos = id % 45, wi = pos / 9, wj2 = pos % 9;
    int sh = (p < 2) ? -2 : 2;
    int sw = (p & 1) ? 4 : -4;
    int hh = nh * 5 + wi - sh;
    if (hh < 0) hh += 20; else if (hh >= 20) hh -= 20;
    int ww2 = nw * 9 + wj2 - sw;
    if (ww2 < 0) ww2 += 36; else if (ww2 >= 36) ww2 -= 36;
    val = ((b * 8 + t) * 20 + hh) * 36 + ww2;
  } else {
    int jj = j - 1320;
    int t = jj / 45, kidx = jj % 45, ki = kidx / 9, kj = kidx % 9;
    int snh = nh + ki - 2, snw = nw + kj - 4;
    if (snh < 0 || snh >= 4 || snw < 0 || snw >= 4) val = -1;
    else val = NTOK + (b * 8 + t) * 16 + snh * 4 + snw;
  }
  ksrc[idx] = val;
}

// ---------- weight convert+transpose (LDS-tiled, both sides coalesced) ----------
// out[n][k] = in[k][n], bf16, zero-pad n>=N.  grid: (ceil(Npad/64), ceil(K/64))
template <int DT>
__global__ void k_wcvt(const int* __restrict__ dflag, const void* __restrict__ in,
                       bf16* __restrict__ out, int K, int N, int Npad) {
  if (*dflag != DT) return;
  __shared__ float t[64][65];
  const int n0 = blockIdx.x * 64;
  const int k0 = blockIdx.y * 64;
  const int tx = threadIdx.x & 63, tg = threadIdx.x >> 6;
#pragma unroll
  for (int r = 0; r < 16; r++) {
    int k = k0 + r * 4 + tg;
    int nn = n0 + tx;
    float v = (k < K && nn < N) ? ldw<DT>(in, (size_t)k * N + nn) : 0.f;
    t[r * 4 + tg][tx] = v;
  }
  __syncthreads();
#pragma unroll
  for (int r = 0; r < 16; r++) {
    int nn = n0 + r * 4 + tg;
    int k = k0 + tx;
    if (nn < Npad && k < K)
      out[(size_t)nn * K + k] = __float2bfloat16(t[tx][r * 4 + tg]);
  }
}

// ---------- bias convert -> f32 ----------
template <int DT>
__global__ void k_bcvt(const int* __restrict__ dflag, const void* __restrict__ in,
                       float* __restrict__ out, int n) {
  if (*dflag != DT) return;
  int i = blockIdx.x * 256 + threadIdx.x;
  if (i < n) out[i] = ldw<DT>(in, i);
}

// ---------- zero one key row (invalid-key target) ----------
__global__ void k_zrow(bf16* __restrict__ p) {
  p[blockIdx.x * 256 + threadIdx.x] = __float2bfloat16(0.f);
}

// ---------- LayerNorm over C=512 ----------
template <int DT, typename InT>
__global__ void k_ln(const int* __restrict__ dflag, const InT* __restrict__ xin,
                     const void* __restrict__ g, const void* __restrict__ be,
                     bf16* __restrict__ out) {
  if (*dflag != DT) return;
  const int tok = blockIdx.x;
  const int tid = threadIdx.x;
  const size_t base = (size_t)tok * C_;
  float v0 = ldf(xin + base + tid);
  float v1 = ldf(xin + base + tid + 256);
  float s = v0 + v1, ss = v0 * v0 + v1 * v1;
#pragma unroll
  for (int o = 32; o; o >>= 1) { s += __shfl_xor(s, o); ss += __shfl_xor(ss, o); }
  __shared__ float sh[10];
  const int lane = tid & 63, wv = tid >> 6;
  if (lane == 0) { sh[wv] = s; sh[4 + wv] = ss; }
  __syncthreads();
  if (tid == 0) {
    float a = sh[0] + sh[1] + sh[2] + sh[3];
    float q = sh[4] + sh[5] + sh[6] + sh[7];
    float mu = a * (1.0f / C_);
    float var = q * (1.0f / C_) - mu * mu;
    sh[8] = mu; sh[9] = rsqrtf(fmaxf(var, 0.f) + 1e-5f);
  }
  __syncthreads();
  float mu = sh[8], inv = sh[9];
  stw(out + base + tid,
      (v0 - mu) * inv * ldw<DT>(g, tid) + ldw<DT>(be, tid));
  stw(out + base + tid + 256,
      (v1 - mu) * inv * ldw<DT>(g, tid + 256) + ldw<DT>(be, tid + 256));
}

// ---------- window pooling ----------
template <int DT>
__global__ void k_pool(const int* __restrict__ dflag, const bf16* __restrict__ xn,
                       const void* __restrict__ wpool, const void* __restrict__ bpool,
                       float* __restrict__ pooled) {
  if (*dflag != DT) return;
  int idx = blockIdx.x * blockDim.x + threadIdx.x;
  if (idx >= 256 * C_) return;
  int c = idx & (C_ - 1);
  int fw = idx >> 9;
  int nw = fw & 3, nh = (fw >> 2) & 3;
  int bt = fw >> 4;
  float acc = ldw<DT>(bpool, 0);
  for (int wi = 0; wi < 5; wi++) {
    int hh = nh * 5 + wi;
    const bf16* base = xn + (((size_t)(bt * 20 + hh)) * 36 + nw * 9) * C_ + c;
    for (int wj = 0; wj < 9; wj++)
      acc += __bfloat162float(base[(size_t)wj * C_]) * ldw<DT>(wpool, wi * 9 + wj);
  }
  pooled[idx] = acc;
}

// ---------- small GEMM pooled(f32) @ wqkv + bqkv -> qkvp_b (bf16, stride 1536) ----------
// grid (6, 32): n0 = bx*256, m0 = by*8; A tile in LDS, B reads coalesced.
template <int DT>
__global__ void k_gemm_small(const int* __restrict__ dflag, const float* __restrict__ A,
                             const void* __restrict__ Bw, const void* __restrict__ bias,
                             bf16* __restrict__ Cc) {
  if (*dflag != DT) return;
  __shared__ float As[8][512];
  const int n = blockIdx.x * 256 + threadIdx.x;
  const int m0 = blockIdx.y * 8;
  for (int i = threadIdx.x; i < 8 * 512; i += 256)
    As[i >> 9][i & 511] = A[(size_t)(m0 + (i >> 9)) * 512 + (i & 511)];
  __syncthreads();
  float acc[8];
  float bv = ldw<DT>(bias, n);
#pragma unroll
  for (int mm = 0; mm < 8; mm++) acc[mm] = bv;
  for (int k = 0; k < 512; k++) {
    float b = ldw<DT>(Bw, (size_t)k * 1536 + n);
#pragma unroll
    for (int mm = 0; mm < 8; mm++) acc[mm] += As[mm][k] * b;
  }
#pragma unroll
  for (int mm = 0; mm < 8; mm++)
    Cc[(size_t)(m0 + mm) * 1536 + n] = __float2bfloat16(acc[mm]);
}

// ---------- MFMA GEMM: out[M][N] = A[M][K](bf16) @ Bt[N][K]^T(bf16) + bias(f32) ----------
template <int DT, int RES, typename OutT>
__global__ __launch_bounds__(256) void k_gemm_m(const int* __restrict__ dflag,
                                                const bf16* __restrict__ A,
                                                const bf16* __restrict__ Bt,
                                                const float* __restrict__ bias,
                                                const void* __restrict__ resid,
                                                OutT* __restrict__ out,
                                                int M, int N, int K) {
  if (dflag && *dflag != DT) return;
  __shared__ __align__(16) unsigned short As[128 * 32];
  __shared__ __align__(16) unsigned short Bs[128 * 32];
  const int tid = threadIdx.x;
  const int lane = tid & 63, wid = tid >> 6;
  const int r15 = lane & 15, quad = lane >> 4;
  const int wm = wid >> 1, wn = wid & 1;
  const int m0 = blockIdx.y * 128, n0 = blockIdx.x * 128;

  f32x4 acc[4][4];
#pragma unroll
  for (int i = 0; i < 4; i++)
#pragma unroll
    for (int j = 0; j < 4; j++)
#pragma unroll
      for (int e = 0; e < 4; e++) acc[i][j][e] = 0.f;

  const int lrow = lane >> 2, lcol = (lane & 3) * 8;

  for (int k0 = 0; k0 < K; k0 += 32) {
    int rem = K - k0;
    if (rem >= 32) {
      const bf16* ga = A + (size_t)(m0 + wid * 32 + lrow) * K + k0 + lcol;
      gload_lds16(ga, &As[wid * 1024]);
      gload_lds16(ga + (size_t)16 * K, &As[wid * 1024 + 512]);
      const bf16* gb = Bt + (size_t)(n0 + wid * 32 + lrow) * K + k0 + lcol;
      gload_lds16(gb, &Bs[wid * 1024]);
      gload_lds16(gb + (size_t)16 * K, &Bs[wid * 1024 + 512]);
    } else {
      int r = tid >> 2, c = (tid & 3) * 8;
      uint4 z = make_uint4(0, 0, 0, 0);
      uint4 a0 = z, a1 = z, b0 = z, b1 = z;
      if (c < rem) {
        a0 = *(const uint4*)(A + (size_t)(m0 + r) * K + k0 + c);
        a1 = *(const uint4*)(A + (size_t)(m0 + r + 64) * K + k0 + c);
        b0 = *(const uint4*)(Bt + (size_t)(n0 + r) * K + k0 + c);
        b1 = *(const uint4*)(Bt + (size_t)(n0 + r + 64) * K + k0 + c);
      }
      *(uint4*)&As[r * 32 + c] = a0;
      *(uint4*)&As[(r + 64) * 32 + c] = a1;
      *(uint4*)&Bs[r * 32 + c] = b0;
      *(uint4*)&Bs[(r + 64) * 32 + c] = b1;
    }
    __syncthreads();

    bf16x8 af[4], bfr[4];
#pragma unroll
    for (int mf = 0; mf < 4; mf++)
      af[mf] = *(const bf16x8*)&As[(wm * 64 + mf * 16 + r15) * 32 + quad * 8];
#pragma unroll
    for (int nf = 0; nf < 4; nf++)
      bfr[nf] = *(const bf16x8*)&Bs[(wn * 64 + nf * 16 + r15) * 32 + quad * 8];
#pragma unroll
    for (int mf = 0; mf < 4; mf++)
#pragma unroll
      for (int nf = 0; nf < 4; nf++)
        acc[mf][nf] = __builtin_amdgcn_mfma_f32_16x16x32_bf16(af[mf], bfr[nf],
                                                              acc[mf][nf], 0, 0, 0);
    __syncthreads();
  }

#pragma unroll
  for (int nf = 0; nf < 4; nf++) {
    int n = n0 + wn * 64 + nf * 16 + r15;
    if (n >= N) continue;
    float bv = bias[n];
#pragma unroll
    for (int mf = 0; mf < 4; mf++) {
      int mb = m0 + wm * 64 + mf * 16 + quad * 4;
#pragma unroll
      for (int e = 0; e < 4; e++) {
        size_t off = (size_t)(mb + e) * N + n;
        float v = acc[mf][nf][e] + bv;
        if (RES == 1) v += ldw<DT>(resid, off);
        else if (RES == 2) v += ((const float*)resid)[off];
        stw(out + off, v);
      }
    }
  }
}

// ---------- MFMA flash attention (384 thr, 6 waves x 32 queries, dbuf) ----------
// grid: (32 windows, 2 qtiles, 4 heads) = 256 blocks (1 per CU)
// LDS-BW optimization: each wave computes TWO 16-query subtiles, so every K/V
// fragment read from LDS feeds 2 MFMAs -> LDS read traffic per tile halves
// (was 12 waves x 32KB = 384KB/tile/CU; now 6 x ~34KB = ~200KB).
// Staging: waves 0-1 stage K (128B/lane, named k0..k7), waves 2-5 stage V^T
// (32-dim chunk, named v0..v3). Named scalars only (promote-alloca hazard).
#define KT 64
#define KPAD 136
#define VPAD 72
#define VST8(VV, DD)                                              \
  vb[(DD + 0) * VPAD + vr] = (unsigned short)(VV.x & 0xFFFFu);    \
  vb[(DD + 1) * VPAD + vr] = (unsigned short)(VV.x >> 16);        \
  vb[(DD + 2) * VPAD + vr] = (unsigned short)(VV.y & 0xFFFFu);    \
  vb[(DD + 3) * VPAD + vr] = (unsigned short)(VV.y >> 16);        \
  vb[(DD + 4) * VPAD + vr] = (unsigned short)(VV.z & 0xFFFFu);    \
  vb[(DD + 5) * VPAD + vr] = (unsigned short)(VV.z >> 16);        \
  vb[(DD + 6) * VPAD + vr] = (unsigned short)(VV.w & 0xFFFFu);    \
  vb[(DD + 7) * VPAD + vr] = (unsigned short)(VV.w >> 16);
__global__ __launch_bounds__(384) void k_attn_m(const bf16* __restrict__ qkv,
                                                const int* __restrict__ ksrc,
                                                bf16* __restrict__ ao) {
  __shared__ int ks_l[NKEY];
  __shared__ __align__(16) unsigned short ktl[2][KT * KPAD];    // K [key][dim]
  __shared__ __align__(16) unsigned short vtl[2][128 * VPAD];   // V^T [dim][key]
  __shared__ __align__(16) unsigned short ptl[6 * 32 * VPAD];   // P per wave [q][key]
  __shared__ float maskv[2][KT];

  const int tid = threadIdx.x;
  const int lane = tid & 63, wid = tid >> 6;   // wid 0..5
  const int r15 = lane & 15, quad = lane >> 4;
  const int w = blockIdx.x, qt = blockIdx.y, n = blockIdx.z;
  const int b = w >> 4, nh = (w >> 2) & 3, nw = w & 3;
  const unsigned short* qkvs = (const unsigned short*)qkv;

  for (int j = tid; j < NKEY; j += 384) ks_l[j] = ksrc[w * NKEY + j];

  // Q A-fragments: 2 subtiles of 16 queries per wave, clamped for padding
  bf16x8 qf[2][4];
#pragma unroll
  for (int s = 0; s < 2; s++) {
    int qw = qt * 192 + wid * 32 + s * 16 + r15;
    int qc2 = qw < 360 ? qw : 359;
    int t = qc2 / 45, pos = qc2 % 45, wi = pos / 9, wj = pos % 9;
    int tok = ((b * 8 + t) * 20 + nh * 5 + wi) * 36 + nw * 9 + wj;
    const unsigned short* qp = qkvs + (size_t)tok * 1536 + n * 128 + quad * 8;
#pragma unroll
    for (int c = 0; c < 4; c++)
      qf[s][c] = *(const bf16x8*)(qp + c * 32);
  }

  f32x4 of[2][8];
#pragma unroll
  for (int s = 0; s < 2; s++)
#pragma unroll
    for (int nt = 0; nt < 8; nt++)
#pragma unroll
      for (int e = 0; e < 4; e++) of[s][nt][e] = 0.f;
  float m_[2][4], l_[2][4];   // l_ per-lane partial, reduced at the end
#pragma unroll
  for (int s = 0; s < 2; s++)
#pragma unroll
    for (int e = 0; e < 4; e++) { m_[s][e] = -1e30f; l_[s][e] = 0.f; }

  unsigned short* ptw = &ptl[wid * 32 * VPAD];

  // staging roles
  const bool isK = (wid < 2);
  const int kr = tid >> 1, kp = tid & 1;   // K role (tid<128): key kr, 128B half kp
  const int vr = lane, vp4 = wid - 2;      // V role (wid>=2): key vr, 32-dim chunk
  // named staging registers (NOT arrays -> guaranteed VGPRs)
  uint4 k0, k1, k2, k3, k4, k5, k6, k7, v0, v1, v2, v3;
  float mreg = -30000.f;
  const unsigned short* kbase = qkvs + 512 + n * 128 + kp * 64;
  const unsigned short* vbase = qkvs + 1024 + n * 128 + vp4 * 32;

  auto load_tile = [&](int j0) {
    int cnt = NKEY - j0; if (cnt > KT) cnt = KT;
    if (isK) {
      int s0 = (kr < cnt) ? ks_l[j0 + kr] : -1;
      mreg = (s0 < 0) ? -30000.f : 0.f;
      int row = (s0 < 0) ? ZROW : s0;
      const uint4* kq = (const uint4*)(kbase + (size_t)row * 1536);
      k0 = kq[0]; k1 = kq[1]; k2 = kq[2]; k3 = kq[3];
      k4 = kq[4]; k5 = kq[5]; k6 = kq[6]; k7 = kq[7];
    } else {
      int s1 = (vr < cnt) ? ks_l[j0 + vr] : -1;
      int row = (s1 < 0) ? ZROW : s1;
      const uint4* vq = (const uint4*)(vbase + (size_t)row * 1536);
      v0 = vq[0]; v1 = vq[1]; v2 = vq[2]; v3 = vq[3];
    }
  };

  auto store_tile = [&](int buf) {
    if (isK) {
      if (kp == 0) maskv[buf][kr] = mreg;
      unsigned short* kb = &ktl[buf][kr * KPAD + kp * 64];
      *(uint4*)&kb[0]  = k0;
      *(uint4*)&kb[8]  = k1;
      *(uint4*)&kb[16] = k2;
      *(uint4*)&kb[24] = k3;
      *(uint4*)&kb[32] = k4;
      *(uint4*)&kb[40] = k5;
      *(uint4*)&kb[48] = k6;
      *(uint4*)&kb[56] = k7;
    } else {
      unsigned short* vb = &vtl[buf][0];
      const int d0 = vp4 * 32;
      VST8(v0, d0)
      VST8(v1, d0 + 8)
      VST8(v2, d0 + 16)
      VST8(v3, d0 + 24)
    }
  };

  __syncthreads();        // ks_l ready
  load_tile(0);
  store_tile(0);
  load_tile(KT);          // prefetch tile 1 into regs (NKEY > KT always)
  __syncthreads();        // buf 0 ready

  int cur = 0, j0 = 0;
  while (true) {
    int nxt = j0 + KT;
    if (nxt < NKEY) {
      store_tile(cur ^ 1);                        // regs (tile nxt) -> idle buffer
      if (nxt + KT < NKEY) load_tile(nxt + KT);   // prefetch tile nxt+KT
    }

    const unsigned short* ktc = &ktl[cur][0];
    const unsigned short* vtc = &vtl[cur][0];
    const float* mkc = maskv[cur];

    // ---- QK^T: each K fragment read once, feeds both subtiles ----
    f32x4 sf[2][4];
#pragma unroll
    for (int s = 0; s < 2; s++)
#pragma unroll
      for (int ft = 0; ft < 4; ft++)
#pragma unroll
        for (int e = 0; e < 4; e++) sf[s][ft][e] = 0.f;
#pragma unroll
    for (int kc = 0; kc < 4; kc++) {
#pragma unroll
      for (int ft = 0; ft < 4; ft++) {
        bf16x8 bb = *(const bf16x8*)&ktc[(ft * 16 + r15) * KPAD + kc * 32 + quad * 8];
        sf[0][ft] = __builtin_amdgcn_mfma_f32_16x16x32_bf16(qf[0][kc], bb, sf[0][ft], 0, 0, 0);
        sf[1][ft] = __builtin_amdgcn_mfma_f32_16x16x32_bf16(qf[1][kc], bb, sf[1][ft], 0, 0, 0);
      }
    }
    const float scl = 0.088388347648318447f;
    // ---- mask+scale & online softmax per subtile ----
#pragma unroll
    for (int s = 0; s < 2; s++) {
#pragma unroll
      for (int ft = 0; ft < 4; ft++) {
        float mk = mkc[ft * 16 + r15];
#pragma unroll
        for (int e = 0; e < 4; e++) sf[s][ft][e] = sf[s][ft][e] * scl + mk;
      }
      float tm[4];
#pragma unroll
      for (int e = 0; e < 4; e++) {
        float v = fmaxf(fmaxf(sf[s][0][e], sf[s][1][e]), fmaxf(sf[s][2][e], sf[s][3][e]));
#pragma unroll
        for (int o = 1; o < 16; o <<= 1) v = fmaxf(v, __shfl_xor(v, o));
        tm[e] = v;
      }
#pragma unroll
      for (int e = 0; e < 4; e++) {
        float mn = fmaxf(m_[s][e], tm[e]);
        float alpha = __expf(m_[s][e] - mn);
        m_[s][e] = mn;
        float rs = 0.f;
#pragma unroll
        for (int ft = 0; ft < 4; ft++) {
          float pv = __expf(sf[s][ft][e] - mn);
          rs += pv;
          ptw[(s * 16 + quad * 4 + e) * VPAD + ft * 16 + r15] = f2bs(pv);
        }
        l_[s][e] = l_[s][e] * alpha + rs;
#pragma unroll
        for (int nt = 0; nt < 8; nt++) of[s][nt][e] *= alpha;
      }
    }
    // ---- PV: each V fragment read once, feeds both subtiles ----
#pragma unroll
    for (int kc = 0; kc < 2; kc++) {
      bf16x8 pa0 = *(const bf16x8*)&ptw[r15 * VPAD + kc * 32 + quad * 8];
      bf16x8 pa1 = *(const bf16x8*)&ptw[(16 + r15) * VPAD + kc * 32 + quad * 8];
#pragma unroll
      for (int nt = 0; nt < 8; nt++) {
        bf16x8 vv = *(const bf16x8*)&vtc[(nt * 16 + r15) * VPAD + kc * 32 + quad * 8];
        of[0][nt] = __builtin_amdgcn_mfma_f32_16x16x32_bf16(pa0, vv, of[0][nt], 0, 0, 0);
        of[1][nt] = __builtin_amdgcn_mfma_f32_16x16x32_bf16(pa1, vv, of[1][nt], 0, 0, 0);
      }
    }

    if (nxt >= NKEY) break;
    __syncthreads();       // all waves done reading buf cur; buf cur^1 fully stored
    cur ^= 1; j0 = nxt;
  }

  // ---- final l reduction + normalize + store ----
#pragma unroll
  for (int s = 0; s < 2; s++)
#pragma unroll
    for (int e = 0; e < 4; e++) {
#pragma unroll
      for (int o = 1; o < 16; o <<= 1) l_[s][e] += __shfl_xor(l_[s][e], o);
    }
#pragma unroll
  for (int s = 0; s < 2; s++)
#pragma unroll
    for (int e = 0; e < 4; e++) {
      int qw = qt * 192 + wid * 32 + s * 16 + quad * 4 + e;
      if (qw >= 360) continue;
      float inv = 1.0f / l_[s][e];
      int t = qw / 45, pos = qw % 45, wi = pos / 9, wj = pos % 9;
      int tok = ((b * 8 + t) * 20 + nh * 5 + wi) * 36 + nw * 9 + wj;
      bf16* op = ao + (size_t)tok * 512 + n * 128 + r15;
#pragma unroll
      for (int nt = 0; nt < 8; nt++)
        stw(op + nt * 16, of[s][nt][e] * inv);
    }
}

// ---------- T2T fold + normalize ----------
__global__ void k_fold(const bf16* __restrict__ h1, float* __restrict__ hf) {
  int idx = blockIdx.x * 256 + threadIdx.x;
  if (idx >= 16 * 40 * 60 * 108) return;
  int x = idx % 108;
  int tmp = idx / 108;
  int y = tmp % 60; tmp /= 60;
  int c = tmp % 40;
  int bt = tmp / 40;
  float sum = 0.f;
  int cnt = 0;
  for (int ki = y % 3; ki < 7; ki += 3) {
    int num = y + 3 - ki;
    if (num < 0) continue;
    int oh = num / 3;
    if (oh >= 20) continue;
    for (int kj = x % 3; kj < 7; kj += 3) {
      int num2 = x + 3 - kj;
      if (num2 < 0) continue;
      int ow = num2 / 3;
      if (ow >= 36) continue;
      sum += __bfloat162float(
          h1[(size_t)(bt * 720 + oh * 36 + ow) * FFN_ + c * 49 + ki * 7 + kj]);
      cnt++;
    }
  }
  hf[idx] = sum / (float)cnt;
}

// ---------- T2T unfold + GELU ----------
__global__ void k_unfold_gelu(const float* __restrict__ hf, bf16* __restrict__ h2) {
  int idx = blockIdx.x * 256 + threadIdx.x;
  if (idx >= NTOK * FFN_) return;
  int f = idx % FFN_;
  int token = idx / FFN_;
  int c = f / 49, k = f % 49, ki = k / 7, kj = k % 7;
  int bt = token / 720, vec = token % 720;
  int oh = vec / 36, ow = vec % 36;
  int y = oh * 3 + ki - 3, x = ow * 3 + kj - 3;
  float v = 0.f;
  if (y >= 0 && y < 60 && x >= 0 && x < 108)
    v = hf[((size_t)(bt * 40 + c) * 60 + y) * 108 + x];
  float g = 0.5f * v * (1.0f + erff(v * 0.70710678118654752f));
  stw(h2 + idx, g);
}

// ---------- launcher ----------
extern "C" void kernel_launch(void* const* d_in, const int* in_sizes, int n_in,
                              void* d_out, int out_size, void* d_ws, size_t ws_size,
                              hipStream_t stream) {
  (void)in_sizes; (void)n_in; (void)out_size; (void)ws_size;
  const void* x     = d_in[0];
  const void* g1    = d_in[1];
  const void* be1   = d_in[2];
  const void* wqkv  = d_in[3];
  const void* bqkv  = d_in[4];
  const void* wproj = d_in[5];
  const void* bproj = d_in[6];
  const void* wpool = d_in[7];
  const void* bpool = d_in[8];
  const void* g2    = d_in[9];
  const void* be2   = d_in[10];
  const void* w1    = d_in[11];
  const void* bf1   = d_in[12];
  const void* w2    = d_in[13];
  const void* bf2   = d_in[14];

  char* ws = (char*)d_ws;
  size_t off = 0;
  auto alloc = [&](size_t bytes) -> void* {
    void* p = ws + off;
    off += (bytes + 255) & ~(size_t)255;
    return p;
  };

  int*   dflag  = (int*)  alloc(256);
  int*   vtab   = (int*)  alloc(NRK * sizeof(int));
  int*   ksrc   = (int*)  alloc((size_t)32 * NKEY * sizeof(int));
  bf16*  buf2   = (bf16*) alloc((size_t)NTOK * FFN_ * 2);   // qkv+qkvp_b -> h1/h2
  float* pooled = (float*)alloc((size_t)256 * C_ * 4);
  float* x2     = (float*)alloc((size_t)NTOK * C_ * 4);
  float* hf     = (float*)alloc((size_t)16 * 40 * 60 * 108 * 4);
  bf16*  wqkv_t = (bf16*) alloc((size_t)1536 * 512 * 2);
  bf16*  wproj_t= (bf16*) alloc((size_t)512 * 512 * 2);
  bf16*  w1_t   = (bf16*) alloc((size_t)2048 * 512 * 2);    // zero-padded 1960->2048
  bf16*  w2_t   = (bf16*) alloc((size_t)512 * FFN_ * 2);
  float* bqkv_f = (float*)alloc(1536 * 4);
  float* bproj_f= (float*)alloc(512 * 4);
  float* bf1_f  = (float*)alloc(FFN_ * 4);
  float* bf2_f  = (float*)alloc(512 * 4);

  bf16* buf1 = (bf16*)d_out;   // xn -> ao -> y scratch (dead before final GEMM)
  bf16* xn = buf1;
  bf16* ao = buf1;
  bf16* y  = buf1;
  bf16* qkv = buf2;
  bf16* h1  = buf2;
  bf16* qkvpb = buf2 + (size_t)NTOK * 1536;   // 257 rows: 256 pooled + 1 zero row

  k_detect<<<1, 64, 0, stream>>>(g1, dflag);
  k_prep<<<1, 64, 0, stream>>>(vtab);
  k_ksrc<<<(32 * NKEY) / 256, 256, 0, stream>>>(vtab, ksrc);
  k_zrow<<<6, 256, 0, stream>>>(qkvpb + (size_t)256 * 1536);

  // weight transpose+convert (LDS-tiled), bias convert (both dtype worlds)
  k_wcvt<0><<<dim3(24, 8), 256, 0, stream>>>(dflag, wqkv, wqkv_t, 512, 1536, 1536);
  k_wcvt<1><<<dim3(24, 8), 256, 0, stream>>>(dflag, wqkv, wqkv_t, 512, 1536, 1536);
  k_wcvt<0><<<dim3(8, 8), 256, 0, stream>>>(dflag, wproj, wproj_t, 512, 512, 512);
  k_wcvt<1><<<dim3(8, 8), 256, 0, stream>>>(dflag, wproj, wproj_t, 512, 512, 512);
  k_wcvt<0><<<dim3(32, 8), 256, 0, stream>>>(dflag, w1, w1_t, 512, FFN_, 2048);
  k_wcvt<1><<<dim3(32, 8), 256, 0, stream>>>(dflag, w1, w1_t, 512, FFN_, 2048);
  k_wcvt<0><<<dim3(8, 31), 256, 0, stream>>>(dflag, w2, w2_t, FFN_, 512, 512);
  k_wcvt<1><<<dim3(8, 31), 256, 0, stream>>>(dflag, w2, w2_t, FFN_, 512, 512);
  k_bcvt<0><<<6, 256, 0, stream>>>(dflag, bqkv, bqkv_f, 1536);
  k_bcvt<1><<<6, 256, 0, stream>>>(dflag, bqkv, bqkv_f, 1536);
  k_bcvt<0><<<2, 256, 0, stream>>>(dflag, bproj, bproj_f, 512);
  k_bcvt<1><<<2, 256, 0, stream>>>(dflag, bproj, bproj_f, 512);
  k_bcvt<0><<<8, 256, 0, stream>>>(dflag, bf1, bf1_f, FFN_);
  k_bcvt<1><<<8, 256, 0, stream>>>(dflag, bf1, bf1_f, FFN_);
  k_bcvt<0><<<2, 256, 0, stream>>>(dflag, bf2, bf2_f, 512);
  k_bcvt<1><<<2, 256, 0, stream>>>(dflag, bf2, bf2_f, 512);

  // LN1
  k_ln<0, bf16><<<NTOK, 256, 0, stream>>>(dflag, (const bf16*)x, g1, be1, xn);
  k_ln<1, float><<<NTOK, 256, 0, stream>>>(dflag, (const float*)x, g1, be1, xn);

  // window pooling
  k_pool<0><<<512, 256, 0, stream>>>(dflag, xn, wpool, bpool, pooled);
  k_pool<1><<<512, 256, 0, stream>>>(dflag, xn, wpool, bpool, pooled);

  // qkv = xn @ wqkv + bqkv
  k_gemm_m<0, 0, bf16><<<dim3(12, 90), 256, 0, stream>>>(
      nullptr, xn, wqkv_t, bqkv_f, nullptr, qkv, NTOK, 1536, 512);

  // qkv_p = pooled @ wqkv + bqkv -> bf16 rows appended after qkv
  k_gemm_small<0><<<dim3(6, 32), 256, 0, stream>>>(dflag, pooled, wqkv, bqkv, qkvpb);
  k_gemm_small<1><<<dim3(6, 32), 256, 0, stream>>>(dflag, pooled, wqkv, bqkv, qkvpb);

  // MFMA flash attention: 256 blocks (1/CU), 6 waves, 32 q/wave
  k_attn_m<<<dim3(32, 2, NH_), 384, 0, stream>>>(qkv, ksrc, ao);

  // x2 = x + ao @ wproj + bproj
  k_gemm_m<0, 1, float><<<dim3(4, 90), 256, 0, stream>>>(
      dflag, ao, wproj_t, bproj_f, x, x2, NTOK, 512, 512);
  k_gemm_m<1, 1, float><<<dim3(4, 90), 256, 0, stream>>>(
      dflag, ao, wproj_t, bproj_f, x, x2, NTOK, 512, 512);

  // LN2 -> y
  k_ln<0, float><<<NTOK, 256, 0, stream>>>(dflag, x2, g2, be2, y);
  k_ln<1, float><<<NTOK, 256, 0, stream>>>(dflag, x2, g2, be2, y);

  // h1 = y @ w1 + bf1
  k_gemm_m<0, 0, bf16><<<dim3(16, 90), 256, 0, stream>>>(
      nullptr, y, w1_t, bf1_f, nullptr, h1, NTOK, FFN_, 512);

  // T2T fold + normalize
  k_fold<<<(16 * 40 * 60 * 108) / 256, 256, 0, stream>>>(h1, hf);

  // T2T unfold + GELU (in place into buf2)
  k_unfold_gelu<<<(NTOK * FFN_) / 256, 256, 0, stream>>>(hf, h1);

  // out = x2 + gelu_h @ w2 + bf2
  k_gemm_m<0, 2, bf16><<<dim3(4, 90), 256, 0, stream>>>(
      dflag, h1, w2_t, bf2_f, x2, (bf16*)d_out, NTOK, 512, FFN_);
  k_gemm_m<1, 2, float><<<dim3(4, 90), 256, 0, stream>>>(
      dflag, h1, w2_t, bf2_f, x2, (float*)d_out, NTOK, 512, FFN_);
}

// Round 6
// 581.372 us; speedup vs baseline: 1.0547x; 1.0547x over previous
//
#include <hip/hip_runtime.h>
#include <hip/hip_bf16.h>
#include <math.h>

typedef __hip_bfloat16 bf16;
typedef __attribute__((ext_vector_type(8))) short bf16x8;
typedef __attribute__((ext_vector_type(4))) float f32x4;

#define DEVI __device__ __forceinline__

// ---------- constants ----------
#define C_ 512
#define NH_ 4
#define NTOK 11520          // B*T*H*W
#define NKEY 1680           // 360 local + 960 rolled + 360 pooled
#define NRK 120
#define FFN_ 1960
#define ZROW (NTOK + 256)   // zeroed key row for invalid slots

// ---------- helpers ----------
DEVI float ldf(const bf16* p) { return __bfloat162float(*p); }
DEVI float ldf(const float* p) { return *p; }
DEVI void stw(bf16* p, float v) { *p = __float2bfloat16(v); }
DEVI void stw(float* p, float v) { *p = v; }
DEVI unsigned short f2bs(float f) { bf16 h = __float2bfloat16(f); return *(unsigned short*)&h; }

// dtype-dispatched scalar load: DT=0 bf16, DT=1 f32
template <int DT> DEVI float ldw(const void* p, size_t i) {
  if (DT == 0) return __bfloat162float(((const bf16*)p)[i]);
  else         return ((const float*)p)[i];
}

// async global->LDS, 16B per lane; lptr is wave-uniform base (HW adds lane*16)
DEVI void gload_lds16(const void* g, void* l) {
  __builtin_amdgcn_global_load_lds(
      (const __attribute__((address_space(1))) void*)g,
      (__attribute__((address_space(3))) void*)l, 16, 0, 0);
}

// ---------- K_init: dtype detect + valid-index table + zero-row ----------
__global__ void k_init(const void* __restrict__ g1, int* __restrict__ flag,
                       int* __restrict__ table, bf16* __restrict__ zp) {
  if (blockIdx.x == 0) {
    if (threadIdx.x == 0) {
      const unsigned short* p = (const unsigned short*)g1;
      *flag = (p[0] == 0x3F80u) ? 0 : 1;
      int cnt = 0;
      for (int pq = 0; pq < 4; pq++)
        for (int wi = 0; wi < 5; wi++)
          for (int wj = 0; wj < 9; wj++) {
            bool invalid;
            if (pq == 0)      invalid = (wi < 3) && (wj < 5);
            else if (pq == 1) invalid = (wi < 3) && (wj >= 4);
            else if (pq == 2) invalid = (wi >= 2) && (wj < 5);
            else              invalid = (wi >= 2) && (wj >= 4);
            if (!invalid) table[cnt++] = pq * 45 + wi * 9 + wj;
          }
    }
  } else {
    zp[(blockIdx.x - 1) * 256 + threadIdx.x] = __float2bfloat16(0.f);
  }
}

// ---------- K0b: per-window key-source table ksrc[32][1680] ----------
// values: token row (<NTOK) for local/rolled, NTOK+pidx for pooled, -1 invalid
__global__ void k_ksrc(const int* __restrict__ vtab, int* __restrict__ ksrc) {
  int idx = blockIdx.x * 256 + threadIdx.x;
  if (idx >= 32 * NKEY) return;
  int w = idx / NKEY, j = idx % NKEY;
  int b = w >> 4, nh = (w >> 2) & 3, nw = w & 3;
  int val;
  if (j < 360) {
    int t = j / 45, pos = j % 45, wi = pos / 9, wj2 = pos % 9;
    val = ((b * 8 + t) * 20 + nh * 5 + wi) * 36 + nw * 9 + wj2;
  } else if (j < 1320) {
    int jj = j - 360;
    int t = jj / 120, r = jj % 120;
    int id = vtab[r];
    int p = id / 45, pos = id % 45, wi = pos / 9, wj2 = pos % 9;
    int sh = (p < 2) ? -2 : 2;
    int sw = (p & 1) ? 4 : -4;
    int hh = nh * 5 + wi - sh;
    if (hh < 0) hh += 20; else if (hh >= 20) hh -= 20;
    int ww2 = nw * 9 + wj2 - sw;
    if (ww2 < 0) ww2 += 36; else if (ww2 >= 36) ww2 -= 36;
    val = ((b * 8 + t) * 20 + hh) * 36 + ww2;
  } else {
    int jj = j - 1320;
    int t = jj / 45, kidx = jj % 45, ki = kidx / 9, kj = kidx % 9;
    int snh = nh + ki - 2, snw = nw + kj - 4;
    if (snh < 0 || snh >= 4 || snw < 0 || snw >= 4) val = -1;
    else val = NTOK + (b * 8 + t) * 16 + snh * 4 + snw;
  }
  ksrc[idx] = val;
}

// ---------- weight convert+transpose (LDS-tiled, both sides coalesced) ----------
// out[n][k] = in[k][n], bf16, zero-pad n>=N.  grid: (ceil(Npad/64), ceil(K/64))
template <int DT>
DEVI void wcvt_body(const void* in, bf16* out, int K, int N, int Npad) {
  __shared__ float t[64][65];
  const int n0 = blockIdx.x * 64;
  const int k0 = blockIdx.y * 64;
  const int tx = threadIdx.x & 63, tg = threadIdx.x >> 6;
#pragma unroll
  for (int r = 0; r < 16; r++) {
    int k = k0 + r * 4 + tg;
    int nn = n0 + tx;
    float v = (k < K && nn < N) ? ldw<DT>(in, (size_t)k * N + nn) : 0.f;
    t[r * 4 + tg][tx] = v;
  }
  __syncthreads();
#pragma unroll
  for (int r = 0; r < 16; r++) {
    int nn = n0 + r * 4 + tg;
    int k = k0 + tx;
    if (nn < Npad && k < K)
      out[(size_t)nn * K + k] = __float2bfloat16(t[tx][r * 4 + tg]);
  }
}
__global__ void k_wcvt(const int* __restrict__ dflag, const void* __restrict__ in,
                       bf16* __restrict__ out, int K, int N, int Npad) {
  if (*dflag == 0) wcvt_body<0>(in, out, K, N, Npad);
  else             wcvt_body<1>(in, out, K, N, Npad);
}

// ---------- bias convert -> f32 ----------
__global__ void k_bcvt(const int* __restrict__ dflag, const void* __restrict__ in,
                       float* __restrict__ out, int n) {
  int i = blockIdx.x * 256 + threadIdx.x;
  if (i < n) out[i] = (*dflag == 0) ? ldw<0>(in, i) : ldw<1>(in, i);
}

// ---------- LayerNorm over C=512 ----------
template <int DTIN, int DTP>
DEVI void ln_body(const void* xin, const void* g, const void* be, bf16* out) {
  const int tok = blockIdx.x;
  const int tid = threadIdx.x;
  const size_t base = (size_t)tok * C_;
  float v0 = ldw<DTIN>(xin, base + tid);
  float v1 = ldw<DTIN>(xin, base + tid + 256);
  float s = v0 + v1, ss = v0 * v0 + v1 * v1;
#pragma unroll
  for (int o = 32; o; o >>= 1) { s += __shfl_xor(s, o); ss += __shfl_xor(ss, o); }
  __shared__ float sh[10];
  const int lane = tid & 63, wv = tid >> 6;
  if (lane == 0) { sh[wv] = s; sh[4 + wv] = ss; }
  __syncthreads();
  if (tid == 0) {
    float a = sh[0] + sh[1] + sh[2] + sh[3];
    float q = sh[4] + sh[5] + sh[6] + sh[7];
    float mu = a * (1.0f / C_);
    float var = q * (1.0f / C_) - mu * mu;
    sh[8] = mu; sh[9] = rsqrtf(fmaxf(var, 0.f) + 1e-5f);
  }
  __syncthreads();
  float mu = sh[8], inv = sh[9];
  stw(out + base + tid,
      (v0 - mu) * inv * ldw<DTP>(g, tid) + ldw<DTP>(be, tid));
  stw(out + base + tid + 256,
      (v1 - mu) * inv * ldw<DTP>(g, tid + 256) + ldw<DTP>(be, tid + 256));
}
// mode 0: input dtype follows dflag (LN1); mode 1: input always f32 (LN2)
__global__ void k_ln(const int* __restrict__ dflag, int mode,
                     const void* __restrict__ xin, const void* __restrict__ g,
                     const void* __restrict__ be, bf16* __restrict__ out) {
  int dt = *dflag;
  if (mode == 0) {
    if (dt == 0) ln_body<0, 0>(xin, g, be, out);
    else         ln_body<1, 1>(xin, g, be, out);
  } else {
    if (dt == 0) ln_body<1, 0>(xin, g, be, out);
    else         ln_body<1, 1>(xin, g, be, out);
  }
}

// ---------- window pooling ----------
template <int DT>
DEVI void pool_body(const bf16* xn, const void* wpool, const void* bpool,
                    float* pooled) {
  int idx = blockIdx.x * blockDim.x + threadIdx.x;
  if (idx >= 256 * C_) return;
  int c = idx & (C_ - 1);
  int fw = idx >> 9;
  int nw = fw & 3, nh = (fw >> 2) & 3;
  int bt = fw >> 4;
  float acc = ldw<DT>(bpool, 0);
  for (int wi = 0; wi < 5; wi++) {
    int hh = nh * 5 + wi;
    const bf16* base = xn + (((size_t)(bt * 20 + hh)) * 36 + nw * 9) * C_ + c;
    for (int wj = 0; wj < 9; wj++)
      acc += __bfloat162float(base[(size_t)wj * C_]) * ldw<DT>(wpool, wi * 9 + wj);
  }
  pooled[idx] = acc;
}
__global__ void k_pool(const int* __restrict__ dflag, const bf16* __restrict__ xn,
                       const void* __restrict__ wpool, const void* __restrict__ bpool,
                       float* __restrict__ pooled) {
  if (*dflag == 0) pool_body<0>(xn, wpool, bpool, pooled);
  else             pool_body<1>(xn, wpool, bpool, pooled);
}

// ---------- small GEMM pooled(f32) @ wqkv + bqkv -> qkvp_b (bf16, stride 1536) ----------
// grid (6, 32): n0 = bx*256, m0 = by*8; A tile in LDS, B reads coalesced.
template <int DT>
DEVI void gemm_small_body(const float* A, const void* Bw, const void* bias,
                          bf16* Cc) {
  __shared__ float As[8][512];
  const int n = blockIdx.x * 256 + threadIdx.x;
  const int m0 = blockIdx.y * 8;
  for (int i = threadIdx.x; i < 8 * 512; i += 256)
    As[i >> 9][i & 511] = A[(size_t)(m0 + (i >> 9)) * 512 + (i & 511)];
  __syncthreads();
  float acc[8];
  float bv = ldw<DT>(bias, n);
#pragma unroll
  for (int mm = 0; mm < 8; mm++) acc[mm] = bv;
  for (int k = 0; k < 512; k++) {
    float b = ldw<DT>(Bw, (size_t)k * 1536 + n);
#pragma unroll
    for (int mm = 0; mm < 8; mm++) acc[mm] += As[mm][k] * b;
  }
#pragma unroll
  for (int mm = 0; mm < 8; mm++)
    Cc[(size_t)(m0 + mm) * 1536 + n] = __float2bfloat16(acc[mm]);
}
__global__ void k_gemm_small(const int* __restrict__ dflag, const float* __restrict__ A,
                             const void* __restrict__ Bw, const void* __restrict__ bias,
                             bf16* __restrict__ Cc) {
  if (*dflag == 0) gemm_small_body<0>(A, Bw, bias, Cc);
  else             gemm_small_body<1>(A, Bw, bias, Cc);
}

// ---------- MFMA GEMM: out[M][N] = A[M][K](bf16) @ Bt[N][K]^T(bf16) + bias(f32) ----------
// RES=0: out bf16.  RES=1: out f32, resid dtype = *dflag.  RES=2: resid f32, out dtype = *dflag.
template <int RES>
__global__ __launch_bounds__(256) void k_gemm_m(const int* __restrict__ dflag,
                                                const bf16* __restrict__ A,
                                                const bf16* __restrict__ Bt,
                                                const float* __restrict__ bias,
                                                const void* __restrict__ resid,
                                                void* __restrict__ out,
                                                int M, int N, int K) {
  const int dt = dflag ? *dflag : 0;
  __shared__ __align__(16) unsigned short As[128 * 32];
  __shared__ __align__(16) unsigned short Bs[128 * 32];
  const int tid = threadIdx.x;
  const int lane = tid & 63, wid = tid >> 6;
  const int r15 = lane & 15, quad = lane >> 4;
  const int wm = wid >> 1, wn = wid & 1;
  const int m0 = blockIdx.y * 128, n0 = blockIdx.x * 128;

  f32x4 acc[4][4];
#pragma unroll
  for (int i = 0; i < 4; i++)
#pragma unroll
    for (int j = 0; j < 4; j++)
#pragma unroll
      for (int e = 0; e < 4; e++) acc[i][j][e] = 0.f;

  const int lrow = lane >> 2, lcol = (lane & 3) * 8;

  for (int k0 = 0; k0 < K; k0 += 32) {
    int rem = K - k0;
    if (rem >= 32) {
      const bf16* ga = A + (size_t)(m0 + wid * 32 + lrow) * K + k0 + lcol;
      gload_lds16(ga, &As[wid * 1024]);
      gload_lds16(ga + (size_t)16 * K, &As[wid * 1024 + 512]);
      const bf16* gb = Bt + (size_t)(n0 + wid * 32 + lrow) * K + k0 + lcol;
      gload_lds16(gb, &Bs[wid * 1024]);
      gload_lds16(gb + (size_t)16 * K, &Bs[wid * 1024 + 512]);
    } else {
      int r = tid >> 2, c = (tid & 3) * 8;
      uint4 z = make_uint4(0, 0, 0, 0);
      uint4 a0 = z, a1 = z, b0 = z, b1 = z;
      if (c < rem) {
        a0 = *(const uint4*)(A + (size_t)(m0 + r) * K + k0 + c);
        a1 = *(const uint4*)(A + (size_t)(m0 + r + 64) * K + k0 + c);
        b0 = *(const uint4*)(Bt + (size_t)(n0 + r) * K + k0 + c);
        b1 = *(const uint4*)(Bt + (size_t)(n0 + r + 64) * K + k0 + c);
      }
      *(uint4*)&As[r * 32 + c] = a0;
      *(uint4*)&As[(r + 64) * 32 + c] = a1;
      *(uint4*)&Bs[r * 32 + c] = b0;
      *(uint4*)&Bs[(r + 64) * 32 + c] = b1;
    }
    __syncthreads();

    bf16x8 af[4], bfr[4];
#pragma unroll
    for (int mf = 0; mf < 4; mf++)
      af[mf] = *(const bf16x8*)&As[(wm * 64 + mf * 16 + r15) * 32 + quad * 8];
#pragma unroll
    for (int nf = 0; nf < 4; nf++)
      bfr[nf] = *(const bf16x8*)&Bs[(wn * 64 + nf * 16 + r15) * 32 + quad * 8];
#pragma unroll
    for (int mf = 0; mf < 4; mf++)
#pragma unroll
      for (int nf = 0; nf < 4; nf++)
        acc[mf][nf] = __builtin_amdgcn_mfma_f32_16x16x32_bf16(af[mf], bfr[nf],
                                                              acc[mf][nf], 0, 0, 0);
    __syncthreads();
  }

#pragma unroll
  for (int nf = 0; nf < 4; nf++) {
    int n = n0 + wn * 64 + nf * 16 + r15;
    if (n >= N) continue;
    float bv = bias[n];
#pragma unroll
    for (int mf = 0; mf < 4; mf++) {
      int mb = m0 + wm * 64 + mf * 16 + quad * 4;
#pragma unroll
      for (int e = 0; e < 4; e++) {
        size_t off = (size_t)(mb + e) * N + n;
        float v = acc[mf][nf][e] + bv;
        if (RES == 1) v += (dt == 0) ? ldw<0>(resid, off) : ldw<1>(resid, off);
        else if (RES == 2) v += ((const float*)resid)[off];
        if (RES == 0) ((bf16*)out)[off] = __float2bfloat16(v);
        else if (RES == 1) ((float*)out)[off] = v;
        else {
          if (dt == 0) ((bf16*)out)[off] = __float2bfloat16(v);
          else         ((float*)out)[off] = v;
        }
      }
    }
  }
}

// ---------- MFMA flash attention (768 thr, 12 waves, K/V double-buffered) ----------
// grid: (32 windows, 2 qtiles, 4 heads) = 256 blocks (1 per CU)
// All key sources (local/rolled/pooled/invalid) are bf16 rows of stride 1536 in
// one array (pooled rows appended at NTOK, zero row at ZROW) -> branch-free staging.
// Staging registers are NAMED SCALARS (k0..k3 / v0,v1), not arrays: prevents the
// promote-alloca pass from spilling them to LDS (R2/R3 regression: LDS_Block_Size
// 107008->156160). Online softmax uses defer-max (THR=8, HK-style): skip the
// O-rescale + max update when no query row grew by >8 (R2 vs R3 evidence: -8us).
#define KT 64
#define KPAD 136
#define VPAD 72
__global__ __launch_bounds__(768) void k_attn_m(const bf16* __restrict__ qkv,
                                                const int* __restrict__ ksrc,
                                                bf16* __restrict__ ao) {
  __shared__ int ks_l[NKEY];
  __shared__ __align__(16) unsigned short ktl[2][KT * KPAD];    // K [key][dim]
  __shared__ __align__(16) unsigned short vtl[2][128 * VPAD];   // V^T [dim][key]
  __shared__ __align__(16) unsigned short ptl[12 * 16 * VPAD];  // P per wave [q][key]
  __shared__ float maskv[2][KT];

  const int tid = threadIdx.x;
  const int lane = tid & 63, wid = tid >> 6;   // wid 0..11
  const int r15 = lane & 15, quad = lane >> 4;
  const int w = blockIdx.x, qt = blockIdx.y, n = blockIdx.z;
  const int b = w >> 4, nh = (w >> 2) & 3, nw = w & 3;
  const unsigned short* qkvs = (const unsigned short*)qkv;

  for (int j = tid; j < NKEY; j += 768) ks_l[j] = ksrc[w * NKEY + j];

  // Q A-fragments (16 queries per wave), clamped for padding
  bf16x8 qf[4];
  {
    int qw = qt * 192 + wid * 16 + r15;
    int qc2 = qw < 360 ? qw : 359;
    int t = qc2 / 45, pos = qc2 % 45, wi = pos / 9, wj = pos % 9;
    int tok = ((b * 8 + t) * 20 + nh * 5 + wi) * 36 + nw * 9 + wj;
    const unsigned short* qp = qkvs + (size_t)tok * 1536 + n * 128 + quad * 8;
#pragma unroll
    for (int c = 0; c < 4; c++)
      qf[c] = *(const bf16x8*)(qp + c * 32);
  }

  f32x4 of[8];
#pragma unroll
  for (int nt = 0; nt < 8; nt++)
#pragma unroll
    for (int e = 0; e < 4; e++) of[nt][e] = 0.f;
  float m_[4], l_[4];   // l_ is a PER-LANE partial sum (reduced once at the end)
#pragma unroll
  for (int e = 0; e < 4; e++) { m_[e] = -1e30f; l_[e] = 0.f; }

  unsigned short* ptw = &ptl[wid * 16 * VPAD];

  // staging roles
  const bool isK = (wid < 4);
  const int kr = tid >> 2, kp = tid & 3;   // K role (tid < 256)
  const int vr = lane, vp8 = wid - 4;      // V role (wid >= 4)
  // named staging registers (NOT arrays -> guaranteed VGPRs)
  uint4 k0, k1, k2, k3, v0, v1;
  float mreg = -30000.f;
  // wave-invariant base offsets
  const unsigned short* kbase = qkvs + 512 + n * 128 + kp * 32;
  const unsigned short* vbase = qkvs + 1024 + n * 128 + vp8 * 16;

  auto load_tile = [&](int j0) {
    int cnt = NKEY - j0; if (cnt > KT) cnt = KT;
    if (isK) {
      int s0 = (kr < cnt) ? ks_l[j0 + kr] : -1;
      mreg = (s0 < 0) ? -30000.f : 0.f;
      int row = (s0 < 0) ? ZROW : s0;
      const uint4* kq = (const uint4*)(kbase + (size_t)row * 1536);
      k0 = kq[0]; k1 = kq[1]; k2 = kq[2]; k3 = kq[3];
    } else {
      int s1 = (vr < cnt) ? ks_l[j0 + vr] : -1;
      int row = (s1 < 0) ? ZROW : s1;
      const uint4* vq = (const uint4*)(vbase + (size_t)row * 1536);
      v0 = vq[0]; v1 = vq[1];
    }
  };

  auto store_tile = [&](int buf) {
    if (isK) {
      if (kp == 0) maskv[buf][kr] = mreg;
      unsigned short* kb = &ktl[buf][kr * KPAD + kp * 32];
      *(uint4*)&kb[0]  = k0;
      *(uint4*)&kb[8]  = k1;
      *(uint4*)&kb[16] = k2;
      *(uint4*)&kb[24] = k3;
    } else {
      unsigned short* vb = &vtl[buf][0];
      int d0 = vp8 * 16;
      vb[(d0 + 0) * VPAD + vr]  = (unsigned short)(v0.x & 0xFFFFu);
      vb[(d0 + 1) * VPAD + vr]  = (unsigned short)(v0.x >> 16);
      vb[(d0 + 2) * VPAD + vr]  = (unsigned short)(v0.y & 0xFFFFu);
      vb[(d0 + 3) * VPAD + vr]  = (unsigned short)(v0.y >> 16);
      vb[(d0 + 4) * VPAD + vr]  = (unsigned short)(v0.z & 0xFFFFu);
      vb[(d0 + 5) * VPAD + vr]  = (unsigned short)(v0.z >> 16);
      vb[(d0 + 6) * VPAD + vr]  = (unsigned short)(v0.w & 0xFFFFu);
      vb[(d0 + 7) * VPAD + vr]  = (unsigned short)(v0.w >> 16);
      vb[(d0 + 8) * VPAD + vr]  = (unsigned short)(v1.x & 0xFFFFu);
      vb[(d0 + 9) * VPAD + vr]  = (unsigned short)(v1.x >> 16);
      vb[(d0 + 10) * VPAD + vr] = (unsigned short)(v1.y & 0xFFFFu);
      vb[(d0 + 11) * VPAD + vr] = (unsigned short)(v1.y >> 16);
      vb[(d0 + 12) * VPAD + vr] = (unsigned short)(v1.z & 0xFFFFu);
      vb[(d0 + 13) * VPAD + vr] = (unsigned short)(v1.z >> 16);
      vb[(d0 + 14) * VPAD + vr] = (unsigned short)(v1.w & 0xFFFFu);
      vb[(d0 + 15) * VPAD + vr] = (unsigned short)(v1.w >> 16);
    }
  };

  __syncthreads();        // ks_l ready
  load_tile(0);
  store_tile(0);
  load_tile(KT);          // prefetch tile 1 into regs (NKEY > KT always)
  __syncthreads();        // buf 0 ready

  int cur = 0, j0 = 0;
  while (true) {
    int nxt = j0 + KT;
    if (nxt < NKEY) {
      store_tile(cur ^ 1);                        // regs (tile nxt) -> idle buffer
      if (nxt + KT < NKEY) load_tile(nxt + KT);   // prefetch tile nxt+KT
    }

    const unsigned short* ktc = &ktl[cur][0];
    const unsigned short* vtc = &vtl[cur][0];
    const float* mkc = maskv[cur];

    // ---- QK^T ----
    f32x4 sf[4];
#pragma unroll
    for (int ft = 0; ft < 4; ft++)
#pragma unroll
      for (int e = 0; e < 4; e++) sf[ft][e] = 0.f;
#pragma unroll
    for (int kc = 0; kc < 4; kc++) {
      bf16x8 a = qf[kc];
#pragma unroll
      for (int ft = 0; ft < 4; ft++) {
        bf16x8 bb = *(const bf16x8*)&ktc[(ft * 16 + r15) * KPAD + kc * 32 + quad * 8];
        sf[ft] = __builtin_amdgcn_mfma_f32_16x16x32_bf16(a, bb, sf[ft], 0, 0, 0);
      }
    }
    const float scl = 0.088388347648318447f;
#pragma unroll
    for (int ft = 0; ft < 4; ft++) {
      float mk = mkc[ft * 16 + r15];
#pragma unroll
      for (int e = 0; e < 4; e++) sf[ft][e] = sf[ft][e] * scl + mk;
    }
    // ---- online softmax (defer-max THR=8; lazy per-lane l partial) ----
    float tm[4];
#pragma unroll
    for (int e = 0; e < 4; e++) {
      float v = fmaxf(fmaxf(sf[0][e], sf[1][e]), fmaxf(sf[2][e], sf[3][e]));
#pragma unroll
      for (int o = 1; o < 16; o <<= 1) v = fmaxf(v, __shfl_xor(v, o));
      tm[e] = v;
    }
    bool grow = (tm[0] > m_[0] + 8.f) | (tm[1] > m_[1] + 8.f) |
                (tm[2] > m_[2] + 8.f) | (tm[3] > m_[3] + 8.f);
    if (__any(grow)) {
#pragma unroll
      for (int e = 0; e < 4; e++) {
        float mn = fmaxf(m_[e], tm[e]);
        float alpha = __expf(m_[e] - mn);
        m_[e] = mn;
        float rs = 0.f;
#pragma unroll
        for (int ft = 0; ft < 4; ft++) {
          float pv = __expf(sf[ft][e] - mn);
          rs += pv;
          ptw[(quad * 4 + e) * VPAD + ft * 16 + r15] = f2bs(pv);
        }
        l_[e] = l_[e] * alpha + rs;
#pragma unroll
        for (int nt = 0; nt < 8; nt++) of[nt][e] *= alpha;
      }
    } else {
#pragma unroll
      for (int e = 0; e < 4; e++) {
        float rs = 0.f;
#pragma unroll
        for (int ft = 0; ft < 4; ft++) {
          float pv = __expf(sf[ft][e] - m_[e]);
          rs += pv;
          ptw[(quad * 4 + e) * VPAD + ft * 16 + r15] = f2bs(pv);
        }
        l_[e] += rs;
      }
    }
    // ---- PV ----
#pragma unroll
    for (int kc = 0; kc < 2; kc++) {
      bf16x8 pa = *(const bf16x8*)&ptw[r15 * VPAD + kc * 32 + quad * 8];
#pragma unroll
      for (int nt = 0; nt < 8; nt++) {
        bf16x8 vb = *(const bf16x8*)&vtc[(nt * 16 + r15) * VPAD + kc * 32 + quad * 8];
        of[nt] = __builtin_amdgcn_mfma_f32_16x16x32_bf16(pa, vb, of[nt], 0, 0, 0);
      }
    }

    if (nxt >= NKEY) break;
    __syncthreads();       // all waves done reading buf cur; buf cur^1 fully stored
    cur ^= 1; j0 = nxt;
  }

  // ---- final l reduction + normalize + store ----
#pragma unroll
  for (int e = 0; e < 4; e++) {
#pragma unroll
    for (int o = 1; o < 16; o <<= 1) l_[e] += __shfl_xor(l_[e], o);
  }
#pragma unroll
  for (int e = 0; e < 4; e++) {
    int qw = qt * 192 + wid * 16 + quad * 4 + e;
    if (qw >= 360) continue;
    float inv = 1.0f / l_[e];
    int t = qw / 45, pos = qw % 45, wi = pos / 9, wj = pos % 9;
    int tok = ((b * 8 + t) * 20 + nh * 5 + wi) * 36 + nw * 9 + wj;
    bf16* op = ao + (size_t)tok * 512 + n * 128 + r15;
#pragma unroll
    for (int nt = 0; nt < 8; nt++)
      stw(op + nt * 16, of[nt][e] * inv);
  }
}

// ---------- T2T fold + normalize ----------
__global__ void k_fold(const bf16* __restrict__ h1, float* __restrict__ hf) {
  int idx = blockIdx.x * 256 + threadIdx.x;
  if (idx >= 16 * 40 * 60 * 108) return;
  int x = idx % 108;
  int tmp = idx / 108;
  int y = tmp % 60; tmp /= 60;
  int c = tmp % 40;
  int bt = tmp / 40;
  float sum = 0.f;
  int cnt = 0;
  for (int ki = y % 3; ki < 7; ki += 3) {
    int num = y + 3 - ki;
    if (num < 0) continue;
    int oh = num / 3;
    if (oh >= 20) continue;
    for (int kj = x % 3; kj < 7; kj += 3) {
      int num2 = x + 3 - kj;
      if (num2 < 0) continue;
      int ow = num2 / 3;
      if (ow >= 36) continue;
      sum += __bfloat162float(
          h1[(size_t)(bt * 720 + oh * 36 + ow) * FFN_ + c * 49 + ki * 7 + kj]);
      cnt++;
    }
  }
  hf[idx] = sum / (float)cnt;
}

// ---------- T2T unfold + GELU ----------
__global__ void k_unfold_gelu(const float* __restrict__ hf, bf16* __restrict__ h2) {
  int idx = blockIdx.x * 256 + threadIdx.x;
  if (idx >= NTOK * FFN_) return;
  int f = idx % FFN_;
  int token = idx / FFN_;
  int c = f / 49, k = f % 49, ki = k / 7, kj = k % 7;
  int bt = token / 720, vec = token % 720;
  int oh = vec / 36, ow = vec % 36;
  int y = oh * 3 + ki - 3, x = ow * 3 + kj - 3;
  float v = 0.f;
  if (y >= 0 && y < 60 && x >= 0 && x < 108)
    v = hf[((size_t)(bt * 40 + c) * 60 + y) * 108 + x];
  float g = 0.5f * v * (1.0f + erff(v * 0.70710678118654752f));
  stw(h2 + idx, g);
}

// ---------- launcher ----------
extern "C" void kernel_launch(void* const* d_in, const int* in_sizes, int n_in,
                              void* d_out, int out_size, void* d_ws, size_t ws_size,
                              hipStream_t stream) {
  (void)in_sizes; (void)n_in; (void)out_size; (void)ws_size;
  const void* x     = d_in[0];
  const void* g1    = d_in[1];
  const void* be1   = d_in[2];
  const void* wqkv  = d_in[3];
  const void* bqkv  = d_in[4];
  const void* wproj = d_in[5];
  const void* bproj = d_in[6];
  const void* wpool = d_in[7];
  const void* bpool = d_in[8];
  const void* g2    = d_in[9];
  const void* be2   = d_in[10];
  const void* w1    = d_in[11];
  const void* bf1   = d_in[12];
  const void* w2    = d_in[13];
  const void* bf2   = d_in[14];

  char* ws = (char*)d_ws;
  size_t off = 0;
  auto alloc = [&](size_t bytes) -> void* {
    void* p = ws + off;
    off += (bytes + 255) & ~(size_t)255;
    return p;
  };

  int*   dflag  = (int*)  alloc(256);
  int*   vtab   = (int*)  alloc(NRK * sizeof(int));
  int*   ksrc   = (int*)  alloc((size_t)32 * NKEY * sizeof(int));
  bf16*  buf2   = (bf16*) alloc((size_t)NTOK * FFN_ * 2);   // qkv+qkvp_b -> h1/h2
  float* pooled = (float*)alloc((size_t)256 * C_ * 4);
  float* x2     = (float*)alloc((size_t)NTOK * C_ * 4);
  float* hf     = (float*)alloc((size_t)16 * 40 * 60 * 108 * 4);
  bf16*  wqkv_t = (bf16*) alloc((size_t)1536 * 512 * 2);
  bf16*  wproj_t= (bf16*) alloc((size_t)512 * 512 * 2);
  bf16*  w1_t   = (bf16*) alloc((size_t)2048 * 512 * 2);    // zero-padded 1960->2048
  bf16*  w2_t   = (bf16*) alloc((size_t)512 * FFN_ * 2);
  float* bqkv_f = (float*)alloc(1536 * 4);
  float* bproj_f= (float*)alloc(512 * 4);
  float* bf1_f  = (float*)alloc(FFN_ * 4);
  float* bf2_f  = (float*)alloc(512 * 4);

  bf16* buf1 = (bf16*)d_out;   // xn -> ao -> y scratch (dead before final GEMM)
  bf16* xn = buf1;
  bf16* ao = buf1;
  bf16* y  = buf1;
  bf16* qkv = buf2;
  bf16* h1  = buf2;
  bf16* qkvpb = buf2 + (size_t)NTOK * 1536;   // 257 rows: 256 pooled + 1 zero row

  // detect + prep + zero-row in one launch
  k_init<<<7, 256, 0, stream>>>(g1, dflag, vtab, qkvpb + (size_t)256 * 1536);
  k_ksrc<<<(32 * NKEY) / 256, 256, 0, stream>>>(vtab, ksrc);

  // weight transpose+convert (LDS-tiled), bias convert (runtime dtype)
  k_wcvt<<<dim3(24, 8), 256, 0, stream>>>(dflag, wqkv, wqkv_t, 512, 1536, 1536);
  k_wcvt<<<dim3(8, 8), 256, 0, stream>>>(dflag, wproj, wproj_t, 512, 512, 512);
  k_wcvt<<<dim3(32, 8), 256, 0, stream>>>(dflag, w1, w1_t, 512, FFN_, 2048);
  k_wcvt<<<dim3(8, 31), 256, 0, stream>>>(dflag, w2, w2_t, FFN_, 512, 512);
  k_bcvt<<<6, 256, 0, stream>>>(dflag, bqkv, bqkv_f, 1536);
  k_bcvt<<<2, 256, 0, stream>>>(dflag, bproj, bproj_f, 512);
  k_bcvt<<<8, 256, 0, stream>>>(dflag, bf1, bf1_f, FFN_);
  k_bcvt<<<2, 256, 0, stream>>>(dflag, bf2, bf2_f, 512);

  // LN1
  k_ln<<<NTOK, 256, 0, stream>>>(dflag, 0, x, g1, be1, xn);

  // window pooling
  k_pool<<<512, 256, 0, stream>>>(dflag, xn, wpool, bpool, pooled);

  // qkv = xn @ wqkv + bqkv
  k_gemm_m<0><<<dim3(12, 90), 256, 0, stream>>>(
      nullptr, xn, wqkv_t, bqkv_f, nullptr, qkv, NTOK, 1536, 512);

  // qkv_p = pooled @ wqkv + bqkv -> bf16 rows appended after qkv
  k_gemm_small<<<dim3(6, 32), 256, 0, stream>>>(dflag, pooled, wqkv, bqkv, qkvpb);

  // MFMA flash attention: 256 blocks (1/CU), 12 waves, 192 queries per block
  k_attn_m<<<dim3(32, 2, NH_), 768, 0, stream>>>(qkv, ksrc, ao);

  // x2 = x + ao @ wproj + bproj
  k_gemm_m<1><<<dim3(4, 90), 256, 0, stream>>>(
      dflag, ao, wproj_t, bproj_f, x, x2, NTOK, 512, 512);

  // LN2 -> y
  k_ln<<<NTOK, 256, 0, stream>>>(dflag, 1, x2, g2, be2, y);

  // h1 = y @ w1 + bf1
  k_gemm_m<0><<<dim3(16, 90), 256, 0, stream>>>(
      nullptr, y, w1_t, bf1_f, nullptr, h1, NTOK, FFN_, 512);

  // T2T fold + normalize
  k_fold<<<(16 * 40 * 60 * 108) / 256, 256, 0, stream>>>(h1, hf);

  // T2T unfold + GELU (in place into buf2)
  k_unfold_gelu<<<(NTOK * FFN_) / 256, 256, 0, stream>>>(hf, h1);

  // out = x2 + gelu_h @ w2 + bf2
  k_gemm_m<2><<<dim3(4, 90), 256, 0, stream>>>(
      dflag, h1, w2_t, bf2_f, x2, d_out, NTOK, 512, FFN_);
}

// Round 7
// 560.122 us; speedup vs baseline: 1.0947x; 1.0379x over previous
//
#include <hip/hip_runtime.h>
#include <hip/hip_bf16.h>
#include <math.h>

typedef __hip_bfloat16 bf16;
typedef __attribute__((ext_vector_type(8))) short bf16x8;
typedef __attribute__((ext_vector_type(4))) float f32x4;

#define DEVI __device__ __forceinline__

// ---------- constants ----------
#define C_ 512
#define NH_ 4
#define NTOK 11520          // B*T*H*W
#define NKEY 1680           // 360 local + 960 rolled + 360 pooled
#define NRK 120
#define FFN_ 1960
#define ZROW (NTOK + 256)   // zeroed key row for invalid slots

// ---------- helpers ----------
DEVI float ldf(const bf16* p) { return __bfloat162float(*p); }
DEVI float ldf(const float* p) { return *p; }
DEVI void stw(bf16* p, float v) { *p = __float2bfloat16(v); }
DEVI void stw(float* p, float v) { *p = v; }
DEVI unsigned short f2bs(float f) { bf16 h = __float2bfloat16(f); return *(unsigned short*)&h; }

// dtype-dispatched scalar load: DT=0 bf16, DT=1 f32
template <int DT> DEVI float ldw(const void* p, size_t i) {
  if (DT == 0) return __bfloat162float(((const bf16*)p)[i]);
  else         return ((const float*)p)[i];
}

// async global->LDS, 16B per lane; lptr is wave-uniform base (HW adds lane*16)
DEVI void gload_lds16(const void* g, void* l) {
  __builtin_amdgcn_global_load_lds(
      (const __attribute__((address_space(1))) void*)g,
      (__attribute__((address_space(3))) void*)l, 16, 0, 0);
}

// ---------- K_init: dtype detect + valid-index table + zero-row ----------
__global__ void k_init(const void* __restrict__ g1, int* __restrict__ flag,
                       int* __restrict__ table, bf16* __restrict__ zp) {
  if (blockIdx.x == 0) {
    if (threadIdx.x == 0) {
      const unsigned short* p = (const unsigned short*)g1;
      *flag = (p[0] == 0x3F80u) ? 0 : 1;
      int cnt = 0;
      for (int pq = 0; pq < 4; pq++)
        for (int wi = 0; wi < 5; wi++)
          for (int wj = 0; wj < 9; wj++) {
            bool invalid;
            if (pq == 0)      invalid = (wi < 3) && (wj < 5);
            else if (pq == 1) invalid = (wi < 3) && (wj >= 4);
            else if (pq == 2) invalid = (wi >= 2) && (wj < 5);
            else              invalid = (wi >= 2) && (wj >= 4);
            if (!invalid) table[cnt++] = pq * 45 + wi * 9 + wj;
          }
    }
  } else {
    zp[(blockIdx.x - 1) * 256 + threadIdx.x] = __float2bfloat16(0.f);
  }
}

// ---------- K0b: per-window key-source table ksrc[32][1680] ----------
// values: token row (<NTOK) for local/rolled, NTOK+pidx for pooled, -1 invalid
__global__ void k_ksrc(const int* __restrict__ vtab, int* __restrict__ ksrc) {
  int idx = blockIdx.x * 256 + threadIdx.x;
  if (idx >= 32 * NKEY) return;
  int w = idx / NKEY, j = idx % NKEY;
  int b = w >> 4, nh = (w >> 2) & 3, nw = w & 3;
  int val;
  if (j < 360) {
    int t = j / 45, pos = j % 45, wi = pos / 9, wj2 = pos % 9;
    val = ((b * 8 + t) * 20 + nh * 5 + wi) * 36 + nw * 9 + wj2;
  } else if (j < 1320) {
    int jj = j - 360;
    int t = jj / 120, r = jj % 120;
    int id = vtab[r];
    int p = id / 45, pos = id % 45, wi = pos / 9, wj2 = pos % 9;
    int sh = (p < 2) ? -2 : 2;
    int sw = (p & 1) ? 4 : -4;
    int hh = nh * 5 + wi - sh;
    if (hh < 0) hh += 20; else if (hh >= 20) hh -= 20;
    int ww2 = nw * 9 + wj2 - sw;
    if (ww2 < 0) ww2 += 36; else if (ww2 >= 36) ww2 -= 36;
    val = ((b * 8 + t) * 20 + hh) * 36 + ww2;
  } else {
    int jj = j - 1320;
    int t = jj / 45, kidx = jj % 45, ki = kidx / 9, kj = kidx % 9;
    int snh = nh + ki - 2, snw = nw + kj - 4;
    if (snh < 0 || snh >= 4 || snw < 0 || snw >= 4) val = -1;
    else val = NTOK + (b * 8 + t) * 16 + snh * 4 + snw;
  }
  ksrc[idx] = val;
}

// ---------- weight convert+transpose (LDS-tiled, both sides coalesced) ----------
// out[n][k] = in[k][n], bf16, zero-pad n>=N.  grid: (ceil(Npad/64), ceil(K/64))
template <int DT>
DEVI void wcvt_body(const void* in, bf16* out, int K, int N, int Npad) {
  __shared__ float t[64][65];
  const int n0 = blockIdx.x * 64;
  const int k0 = blockIdx.y * 64;
  const int tx = threadIdx.x & 63, tg = threadIdx.x >> 6;
#pragma unroll
  for (int r = 0; r < 16; r++) {
    int k = k0 + r * 4 + tg;
    int nn = n0 + tx;
    float v = (k < K && nn < N) ? ldw<DT>(in, (size_t)k * N + nn) : 0.f;
    t[r * 4 + tg][tx] = v;
  }
  __syncthreads();
#pragma unroll
  for (int r = 0; r < 16; r++) {
    int nn = n0 + r * 4 + tg;
    int k = k0 + tx;
    if (nn < Npad && k < K)
      out[(size_t)nn * K + k] = __float2bfloat16(t[tx][r * 4 + tg]);
  }
}
__global__ void k_wcvt(const int* __restrict__ dflag, const void* __restrict__ in,
                       bf16* __restrict__ out, int K, int N, int Npad) {
  if (*dflag == 0) wcvt_body<0>(in, out, K, N, Npad);
  else             wcvt_body<1>(in, out, K, N, Npad);
}

// ---------- bias convert -> f32 (all four biases in one launch) ----------
// grid 18 blocks: [0,6)=bqkv(1536) [6,8)=bproj(512) [8,16)=bf1(1960 pad) [16,18)=bf2(512)
__global__ void k_bcvt4(const int* __restrict__ dflag,
                        const void* __restrict__ b0, float* __restrict__ o0,
                        const void* __restrict__ b1, float* __restrict__ o1,
                        const void* __restrict__ b2, float* __restrict__ o2,
                        const void* __restrict__ b3, float* __restrict__ o3) {
  int dt = *dflag;
  int bx = blockIdx.x;
  const void* src; float* dst; int n, i;
  if (bx < 6)       { src = b0; dst = o0; n = 1536; i = bx * 256 + threadIdx.x; }
  else if (bx < 8)  { src = b1; dst = o1; n = 512;  i = (bx - 6) * 256 + threadIdx.x; }
  else if (bx < 16) { src = b2; dst = o2; n = FFN_; i = (bx - 8) * 256 + threadIdx.x; }
  else              { src = b3; dst = o3; n = 512;  i = (bx - 16) * 256 + threadIdx.x; }
  if (i < n) dst[i] = (dt == 0) ? ldw<0>(src, i) : ldw<1>(src, i);
}

// ---------- LayerNorm over C=512 ----------
template <int DTIN, int DTP>
DEVI void ln_body(const void* xin, const void* g, const void* be, bf16* out) {
  const int tok = blockIdx.x;
  const int tid = threadIdx.x;
  const size_t base = (size_t)tok * C_;
  float v0 = ldw<DTIN>(xin, base + tid);
  float v1 = ldw<DTIN>(xin, base + tid + 256);
  float s = v0 + v1, ss = v0 * v0 + v1 * v1;
#pragma unroll
  for (int o = 32; o; o >>= 1) { s += __shfl_xor(s, o); ss += __shfl_xor(ss, o); }
  __shared__ float sh[10];
  const int lane = tid & 63, wv = tid >> 6;
  if (lane == 0) { sh[wv] = s; sh[4 + wv] = ss; }
  __syncthreads();
  if (tid == 0) {
    float a = sh[0] + sh[1] + sh[2] + sh[3];
    float q = sh[4] + sh[5] + sh[6] + sh[7];
    float mu = a * (1.0f / C_);
    float var = q * (1.0f / C_) - mu * mu;
    sh[8] = mu; sh[9] = rsqrtf(fmaxf(var, 0.f) + 1e-5f);
  }
  __syncthreads();
  float mu = sh[8], inv = sh[9];
  stw(out + base + tid,
      (v0 - mu) * inv * ldw<DTP>(g, tid) + ldw<DTP>(be, tid));
  stw(out + base + tid + 256,
      (v1 - mu) * inv * ldw<DTP>(g, tid + 256) + ldw<DTP>(be, tid + 256));
}
// mode 0: input dtype follows dflag (LN1); mode 1: input always f32 (LN2)
__global__ void k_ln(const int* __restrict__ dflag, int mode,
                     const void* __restrict__ xin, const void* __restrict__ g,
                     const void* __restrict__ be, bf16* __restrict__ out) {
  int dt = *dflag;
  if (mode == 0) {
    if (dt == 0) ln_body<0, 0>(xin, g, be, out);
    else         ln_body<1, 1>(xin, g, be, out);
  } else {
    if (dt == 0) ln_body<1, 0>(xin, g, be, out);
    else         ln_body<1, 1>(xin, g, be, out);
  }
}

// ---------- window pooling ----------
template <int DT>
DEVI void pool_body(const bf16* xn, const void* wpool, const void* bpool,
                    float* pooled) {
  int idx = blockIdx.x * blockDim.x + threadIdx.x;
  if (idx >= 256 * C_) return;
  int c = idx & (C_ - 1);
  int fw = idx >> 9;
  int nw = fw & 3, nh = (fw >> 2) & 3;
  int bt = fw >> 4;
  float acc = ldw<DT>(bpool, 0);
  for (int wi = 0; wi < 5; wi++) {
    int hh = nh * 5 + wi;
    const bf16* base = xn + (((size_t)(bt * 20 + hh)) * 36 + nw * 9) * C_ + c;
    for (int wj = 0; wj < 9; wj++)
      acc += __bfloat162float(base[(size_t)wj * C_]) * ldw<DT>(wpool, wi * 9 + wj);
  }
  pooled[idx] = acc;
}
__global__ void k_pool(const int* __restrict__ dflag, const bf16* __restrict__ xn,
                       const void* __restrict__ wpool, const void* __restrict__ bpool,
                       float* __restrict__ pooled) {
  if (*dflag == 0) pool_body<0>(xn, wpool, bpool, pooled);
  else             pool_body<1>(xn, wpool, bpool, pooled);
}

// ---------- small GEMM pooled(f32) @ wqkv + bqkv -> qkvp_b (bf16, stride 1536) ----------
// grid (6, 32): n0 = bx*256, m0 = by*8; A tile in LDS, B reads coalesced.
template <int DT>
DEVI void gemm_small_body(const float* A, const void* Bw, const void* bias,
                          bf16* Cc) {
  __shared__ float As[8][512];
  const int n = blockIdx.x * 256 + threadIdx.x;
  const int m0 = blockIdx.y * 8;
  for (int i = threadIdx.x; i < 8 * 512; i += 256)
    As[i >> 9][i & 511] = A[(size_t)(m0 + (i >> 9)) * 512 + (i & 511)];
  __syncthreads();
  float acc[8];
  float bv = ldw<DT>(bias, n);
#pragma unroll
  for (int mm = 0; mm < 8; mm++) acc[mm] = bv;
  for (int k = 0; k < 512; k++) {
    float b = ldw<DT>(Bw, (size_t)k * 1536 + n);
#pragma unroll
    for (int mm = 0; mm < 8; mm++) acc[mm] += As[mm][k] * b;
  }
#pragma unroll
  for (int mm = 0; mm < 8; mm++)
    Cc[(size_t)(m0 + mm) * 1536 + n] = __float2bfloat16(acc[mm]);
}
__global__ void k_gemm_small(const int* __restrict__ dflag, const float* __restrict__ A,
                             const void* __restrict__ Bw, const void* __restrict__ bias,
                             bf16* __restrict__ Cc) {
  if (*dflag == 0) gemm_small_body<0>(A, Bw, bias, Cc);
  else             gemm_small_body<1>(A, Bw, bias, Cc);
}

// ---------- MFMA GEMM: out[M][N] = A[M][K](bf16) @ Bt[N][K]^T(bf16) + bias(f32) ----------
// BK=64 as two [128][32] chunks (keeps proven 64B-row LDS layout / bank behavior)
// -> one barrier pair per 64-k step: halves the 2-phase vmcnt(0)+barrier drains
// (m233: stage+drain is ~72% of a 2-phase K-loop's critical path).
// RES=0: out bf16.  RES=1: out f32, resid dtype = *dflag.  RES=2: resid f32, out dtype = *dflag.
template <int RES>
__global__ __launch_bounds__(256) void k_gemm_m(const int* __restrict__ dflag,
                                                const bf16* __restrict__ A,
                                                const bf16* __restrict__ Bt,
                                                const float* __restrict__ bias,
                                                const void* __restrict__ resid,
                                                void* __restrict__ out,
                                                int M, int N, int K) {
  const int dt = dflag ? *dflag : 0;
  __shared__ __align__(16) unsigned short As[2][128 * 32];
  __shared__ __align__(16) unsigned short Bs[2][128 * 32];
  const int tid = threadIdx.x;
  const int lane = tid & 63, wid = tid >> 6;
  const int r15 = lane & 15, quad = lane >> 4;
  const int wm = wid >> 1, wn = wid & 1;
  const int m0 = blockIdx.y * 128, n0 = blockIdx.x * 128;

  f32x4 acc[4][4];
#pragma unroll
  for (int i = 0; i < 4; i++)
#pragma unroll
    for (int j = 0; j < 4; j++)
#pragma unroll
      for (int e = 0; e < 4; e++) acc[i][j][e] = 0.f;

  const int lrow = lane >> 2, lcol = (lane & 3) * 8;

  for (int k0 = 0; k0 < K; k0 += 64) {
    int rem = K - k0;
    if (rem >= 64) {
      const bf16* ga = A + (size_t)(m0 + wid * 32 + lrow) * K + k0 + lcol;
      gload_lds16(ga, &As[0][wid * 1024]);
      gload_lds16(ga + (size_t)16 * K, &As[0][wid * 1024 + 512]);
      gload_lds16(ga + 32, &As[1][wid * 1024]);
      gload_lds16(ga + (size_t)16 * K + 32, &As[1][wid * 1024 + 512]);
      const bf16* gb = Bt + (size_t)(n0 + wid * 32 + lrow) * K + k0 + lcol;
      gload_lds16(gb, &Bs[0][wid * 1024]);
      gload_lds16(gb + (size_t)16 * K, &Bs[0][wid * 1024 + 512]);
      gload_lds16(gb + 32, &Bs[1][wid * 1024]);
      gload_lds16(gb + (size_t)16 * K + 32, &Bs[1][wid * 1024 + 512]);
    } else {
      // tail (rem multiple of 8, < 64): 32 rows x 64 cols per pass, 4 passes
      int r = tid >> 3, c = (tid & 7) * 8;
      uint4 z = make_uint4(0, 0, 0, 0);
      int h = c >> 5, cc = c & 31;
#pragma unroll
      for (int p = 0; p < 4; p++) {
        int row = r + p * 32;
        uint4 av = z, bv = z;
        if (c < rem) {
          av = *(const uint4*)(A + (size_t)(m0 + row) * K + k0 + c);
          bv = *(const uint4*)(Bt + (size_t)(n0 + row) * K + k0 + c);
        }
        *(uint4*)&As[h][row * 32 + cc] = av;
        *(uint4*)&Bs[h][row * 32 + cc] = bv;
      }
    }
    __syncthreads();

#pragma unroll
    for (int h = 0; h < 2; h++) {
      bf16x8 af[4], bfr[4];
#pragma unroll
      for (int mf = 0; mf < 4; mf++)
        af[mf] = *(const bf16x8*)&As[h][(wm * 64 + mf * 16 + r15) * 32 + quad * 8];
#pragma unroll
      for (int nf = 0; nf < 4; nf++)
        bfr[nf] = *(const bf16x8*)&Bs[h][(wn * 64 + nf * 16 + r15) * 32 + quad * 8];
#pragma unroll
      for (int mf = 0; mf < 4; mf++)
#pragma unroll
        for (int nf = 0; nf < 4; nf++)
          acc[mf][nf] = __builtin_amdgcn_mfma_f32_16x16x32_bf16(af[mf], bfr[nf],
                                                                acc[mf][nf], 0, 0, 0);
    }
    __syncthreads();
  }

#pragma unroll
  for (int nf = 0; nf < 4; nf++) {
    int n = n0 + wn * 64 + nf * 16 + r15;
    if (n >= N) continue;
    float bv = bias[n];
#pragma unroll
    for (int mf = 0; mf < 4; mf++) {
      int mb = m0 + wm * 64 + mf * 16 + quad * 4;
#pragma unroll
      for (int e = 0; e < 4; e++) {
        size_t off = (size_t)(mb + e) * N + n;
        float v = acc[mf][nf][e] + bv;
        if (RES == 1) v += (dt == 0) ? ldw<0>(resid, off) : ldw<1>(resid, off);
        else if (RES == 2) v += ((const float*)resid)[off];
        if (RES == 0) ((bf16*)out)[off] = __float2bfloat16(v);
        else if (RES == 1) ((float*)out)[off] = v;
        else {
          if (dt == 0) ((bf16*)out)[off] = __float2bfloat16(v);
          else         ((float*)out)[off] = v;
        }
      }
    }
  }
}

// ---------- MFMA flash attention (768 thr, 12 waves, K/V double-buffered) ----------
// grid: (32 windows, 2 qtiles, 4 heads) = 256 blocks (1 per CU)
// All key sources (local/rolled/pooled/invalid) are bf16 rows of stride 1536 in
// one array (pooled rows appended at NTOK, zero row at ZROW) -> branch-free staging.
// Staging registers are NAMED SCALARS (k0..k3 / v0,v1), not arrays: prevents the
// promote-alloca pass from spilling them to LDS (R2/R3 regression: LDS_Block_Size
// 107008->156160). Online softmax uses defer-max (THR=8, HK-style): skip the
// O-rescale + max update when no query row grew by >8 (R2 vs R3 evidence: -8us).
#define KT 64
#define KPAD 136
#define VPAD 72
__global__ __launch_bounds__(768) void k_attn_m(const bf16* __restrict__ qkv,
                                                const int* __restrict__ ksrc,
                                                bf16* __restrict__ ao) {
  __shared__ int ks_l[NKEY];
  __shared__ __align__(16) unsigned short ktl[2][KT * KPAD];    // K [key][dim]
  __shared__ __align__(16) unsigned short vtl[2][128 * VPAD];   // V^T [dim][key]
  __shared__ __align__(16) unsigned short ptl[12 * 16 * VPAD];  // P per wave [q][key]
  __shared__ float maskv[2][KT];

  const int tid = threadIdx.x;
  const int lane = tid & 63, wid = tid >> 6;   // wid 0..11
  const int r15 = lane & 15, quad = lane >> 4;
  const int w = blockIdx.x, qt = blockIdx.y, n = blockIdx.z;
  const int b = w >> 4, nh = (w >> 2) & 3, nw = w & 3;
  const unsigned short* qkvs = (const unsigned short*)qkv;

  for (int j = tid; j < NKEY; j += 768) ks_l[j] = ksrc[w * NKEY + j];

  // Q A-fragments (16 queries per wave), clamped for padding
  bf16x8 qf[4];
  {
    int qw = qt * 192 + wid * 16 + r15;
    int qc2 = qw < 360 ? qw : 359;
    int t = qc2 / 45, pos = qc2 % 45, wi = pos / 9, wj = pos % 9;
    int tok = ((b * 8 + t) * 20 + nh * 5 + wi) * 36 + nw * 9 + wj;
    const unsigned short* qp = qkvs + (size_t)tok * 1536 + n * 128 + quad * 8;
#pragma unroll
    for (int c = 0; c < 4; c++)
      qf[c] = *(const bf16x8*)(qp + c * 32);
  }

  f32x4 of[8];
#pragma unroll
  for (int nt = 0; nt < 8; nt++)
#pragma unroll
    for (int e = 0; e < 4; e++) of[nt][e] = 0.f;
  float m_[4], l_[4];   // l_ is a PER-LANE partial sum (reduced once at the end)
#pragma unroll
  for (int e = 0; e < 4; e++) { m_[e] = -1e30f; l_[e] = 0.f; }

  unsigned short* ptw = &ptl[wid * 16 * VPAD];

  // staging roles
  const bool isK = (wid < 4);
  const int kr = tid >> 2, kp = tid & 3;   // K role (tid < 256)
  const int vr = lane, vp8 = wid - 4;      // V role (wid >= 4)
  // named staging registers (NOT arrays -> guaranteed VGPRs)
  uint4 k0, k1, k2, k3, v0, v1;
  float mreg = -30000.f;
  // wave-invariant base offsets
  const unsigned short* kbase = qkvs + 512 + n * 128 + kp * 32;
  const unsigned short* vbase = qkvs + 1024 + n * 128 + vp8 * 16;

  auto load_tile = [&](int j0) {
    int cnt = NKEY - j0; if (cnt > KT) cnt = KT;
    if (isK) {
      int s0 = (kr < cnt) ? ks_l[j0 + kr] : -1;
      mreg = (s0 < 0) ? -30000.f : 0.f;
      int row = (s0 < 0) ? ZROW : s0;
      const uint4* kq = (const uint4*)(kbase + (size_t)row * 1536);
      k0 = kq[0]; k1 = kq[1]; k2 = kq[2]; k3 = kq[3];
    } else {
      int s1 = (vr < cnt) ? ks_l[j0 + vr] : -1;
      int row = (s1 < 0) ? ZROW : s1;
      const uint4* vq = (const uint4*)(vbase + (size_t)row * 1536);
      v0 = vq[0]; v1 = vq[1];
    }
  };

  auto store_tile = [&](int buf) {
    if (isK) {
      if (kp == 0) maskv[buf][kr] = mreg;
      unsigned short* kb = &ktl[buf][kr * KPAD + kp * 32];
      *(uint4*)&kb[0]  = k0;
      *(uint4*)&kb[8]  = k1;
      *(uint4*)&kb[16] = k2;
      *(uint4*)&kb[24] = k3;
    } else {
      unsigned short* vb = &vtl[buf][0];
      int d0 = vp8 * 16;
      vb[(d0 + 0) * VPAD + vr]  = (unsigned short)(v0.x & 0xFFFFu);
      vb[(d0 + 1) * VPAD + vr]  = (unsigned short)(v0.x >> 16);
      vb[(d0 + 2) * VPAD + vr]  = (unsigned short)(v0.y & 0xFFFFu);
      vb[(d0 + 3) * VPAD + vr]  = (unsigned short)(v0.y >> 16);
      vb[(d0 + 4) * VPAD + vr]  = (unsigned short)(v0.z & 0xFFFFu);
      vb[(d0 + 5) * VPAD + vr]  = (unsigned short)(v0.z >> 16);
      vb[(d0 + 6) * VPAD + vr]  = (unsigned short)(v0.w & 0xFFFFu);
      vb[(d0 + 7) * VPAD + vr]  = (unsigned short)(v0.w >> 16);
      vb[(d0 + 8) * VPAD + vr]  = (unsigned short)(v1.x & 0xFFFFu);
      vb[(d0 + 9) * VPAD + vr]  = (unsigned short)(v1.x >> 16);
      vb[(d0 + 10) * VPAD + vr] = (unsigned short)(v1.y & 0xFFFFu);
      vb[(d0 + 11) * VPAD + vr] = (unsigned short)(v1.y >> 16);
      vb[(d0 + 12) * VPAD + vr] = (unsigned short)(v1.z & 0xFFFFu);
      vb[(d0 + 13) * VPAD + vr] = (unsigned short)(v1.z >> 16);
      vb[(d0 + 14) * VPAD + vr] = (unsigned short)(v1.w & 0xFFFFu);
      vb[(d0 + 15) * VPAD + vr] = (unsigned short)(v1.w >> 16);
    }
  };

  __syncthreads();        // ks_l ready
  load_tile(0);
  store_tile(0);
  load_tile(KT);          // prefetch tile 1 into regs (NKEY > KT always)
  __syncthreads();        // buf 0 ready

  int cur = 0, j0 = 0;
  while (true) {
    int nxt = j0 + KT;
    if (nxt < NKEY) {
      store_tile(cur ^ 1);                        // regs (tile nxt) -> idle buffer
      if (nxt + KT < NKEY) load_tile(nxt + KT);   // prefetch tile nxt+KT
    }

    const unsigned short* ktc = &ktl[cur][0];
    const unsigned short* vtc = &vtl[cur][0];
    const float* mkc = maskv[cur];

    // ---- QK^T ----
    f32x4 sf[4];
#pragma unroll
    for (int ft = 0; ft < 4; ft++)
#pragma unroll
      for (int e = 0; e < 4; e++) sf[ft][e] = 0.f;
#pragma unroll
    for (int kc = 0; kc < 4; kc++) {
      bf16x8 a = qf[kc];
#pragma unroll
      for (int ft = 0; ft < 4; ft++) {
        bf16x8 bb = *(const bf16x8*)&ktc[(ft * 16 + r15) * KPAD + kc * 32 + quad * 8];
        sf[ft] = __builtin_amdgcn_mfma_f32_16x16x32_bf16(a, bb, sf[ft], 0, 0, 0);
      }
    }
    const float scl = 0.088388347648318447f;
#pragma unroll
    for (int ft = 0; ft < 4; ft++) {
      float mk = mkc[ft * 16 + r15];
#pragma unroll
      for (int e = 0; e < 4; e++) sf[ft][e] = sf[ft][e] * scl + mk;
    }
    // ---- online softmax (defer-max THR=8; lazy per-lane l partial) ----
    float tm[4];
#pragma unroll
    for (int e = 0; e < 4; e++) {
      float v = fmaxf(fmaxf(sf[0][e], sf[1][e]), fmaxf(sf[2][e], sf[3][e]));
#pragma unroll
      for (int o = 1; o < 16; o <<= 1) v = fmaxf(v, __shfl_xor(v, o));
      tm[e] = v;
    }
    bool grow = (tm[0] > m_[0] + 8.f) | (tm[1] > m_[1] + 8.f) |
                (tm[2] > m_[2] + 8.f) | (tm[3] > m_[3] + 8.f);
    if (__any(grow)) {
#pragma unroll
      for (int e = 0; e < 4; e++) {
        float mn = fmaxf(m_[e], tm[e]);
        float alpha = __expf(m_[e] - mn);
        m_[e] = mn;
        float rs = 0.f;
#pragma unroll
        for (int ft = 0; ft < 4; ft++) {
          float pv = __expf(sf[ft][e] - mn);
          rs += pv;
          ptw[(quad * 4 + e) * VPAD + ft * 16 + r15] = f2bs(pv);
        }
        l_[e] = l_[e] * alpha + rs;
#pragma unroll
        for (int nt = 0; nt < 8; nt++) of[nt][e] *= alpha;
      }
    } else {
#pragma unroll
      for (int e = 0; e < 4; e++) {
        float rs = 0.f;
#pragma unroll
        for (int ft = 0; ft < 4; ft++) {
          float pv = __expf(sf[ft][e] - m_[e]);
          rs += pv;
          ptw[(quad * 4 + e) * VPAD + ft * 16 + r15] = f2bs(pv);
        }
        l_[e] += rs;
      }
    }
    // ---- PV ----
#pragma unroll
    for (int kc = 0; kc < 2; kc++) {
      bf16x8 pa = *(const bf16x8*)&ptw[r15 * VPAD + kc * 32 + quad * 8];
#pragma unroll
      for (int nt = 0; nt < 8; nt++) {
        bf16x8 vb = *(const bf16x8*)&vtc[(nt * 16 + r15) * VPAD + kc * 32 + quad * 8];
        of[nt] = __builtin_amdgcn_mfma_f32_16x16x32_bf16(pa, vb, of[nt], 0, 0, 0);
      }
    }

    if (nxt >= NKEY) break;
    __syncthreads();       // all waves done reading buf cur; buf cur^1 fully stored
    cur ^= 1; j0 = nxt;
  }

  // ---- final l reduction + normalize + store ----
#pragma unroll
  for (int e = 0; e < 4; e++) {
#pragma unroll
    for (int o = 1; o < 16; o <<= 1) l_[e] += __shfl_xor(l_[e], o);
  }
#pragma unroll
  for (int e = 0; e < 4; e++) {
    int qw = qt * 192 + wid * 16 + quad * 4 + e;
    if (qw >= 360) continue;
    float inv = 1.0f / l_[e];
    int t = qw / 45, pos = qw % 45, wi = pos / 9, wj = pos % 9;
    int tok = ((b * 8 + t) * 20 + nh * 5 + wi) * 36 + nw * 9 + wj;
    bf16* op = ao + (size_t)tok * 512 + n * 128 + r15;
#pragma unroll
    for (int nt = 0; nt < 8; nt++)
      stw(op + nt * 16, of[nt][e] * inv);
  }
}

// ---------- T2T fold + normalize ----------
__global__ void k_fold(const bf16* __restrict__ h1, float* __restrict__ hf) {
  int idx = blockIdx.x * 256 + threadIdx.x;
  if (idx >= 16 * 40 * 60 * 108) return;
  int x = idx % 108;
  int tmp = idx / 108;
  int y = tmp % 60; tmp /= 60;
  int c = tmp % 40;
  int bt = tmp / 40;
  float sum = 0.f;
  int cnt = 0;
  for (int ki = y % 3; ki < 7; ki += 3) {
    int num = y + 3 - ki;
    if (num < 0) continue;
    int oh = num / 3;
    if (oh >= 20) continue;
    for (int kj = x % 3; kj < 7; kj += 3) {
      int num2 = x + 3 - kj;
      if (num2 < 0) continue;
      int ow = num2 / 3;
      if (ow >= 36) continue;
      sum += __bfloat162float(
          h1[(size_t)(bt * 720 + oh * 36 + ow) * FFN_ + c * 49 + ki * 7 + kj]);
      cnt++;
    }
  }
  hf[idx] = sum / (float)cnt;
}

// ---------- T2T unfold + GELU ----------
__global__ void k_unfold_gelu(const float* __restrict__ hf, bf16* __restrict__ h2) {
  int idx = blockIdx.x * 256 + threadIdx.x;
  if (idx >= NTOK * FFN_) return;
  int f = idx % FFN_;
  int token = idx / FFN_;
  int c = f / 49, k = f % 49, ki = k / 7, kj = k % 7;
  int bt = token / 720, vec = token % 720;
  int oh = vec / 36, ow = vec % 36;
  int y = oh * 3 + ki - 3, x = ow * 3 + kj - 3;
  float v = 0.f;
  if (y >= 0 && y < 60 && x >= 0 && x < 108)
    v = hf[((size_t)(bt * 40 + c) * 60 + y) * 108 + x];
  float g = 0.5f * v * (1.0f + erff(v * 0.70710678118654752f));
  stw(h2 + idx, g);
}

// ---------- launcher ----------
extern "C" void kernel_launch(void* const* d_in, const int* in_sizes, int n_in,
                              void* d_out, int out_size, void* d_ws, size_t ws_size,
                              hipStream_t stream) {
  (void)in_sizes; (void)n_in; (void)out_size; (void)ws_size;
  const void* x     = d_in[0];
  const void* g1    = d_in[1];
  const void* be1   = d_in[2];
  const void* wqkv  = d_in[3];
  const void* bqkv  = d_in[4];
  const void* wproj = d_in[5];
  const void* bproj = d_in[6];
  const void* wpool = d_in[7];
  const void* bpool = d_in[8];
  const void* g2    = d_in[9];
  const void* be2   = d_in[10];
  const void* w1    = d_in[11];
  const void* bf1   = d_in[12];
  const void* w2    = d_in[13];
  const void* bf2   = d_in[14];

  char* ws = (char*)d_ws;
  size_t off = 0;
  auto alloc = [&](size_t bytes) -> void* {
    void* p = ws + off;
    off += (bytes + 255) & ~(size_t)255;
    return p;
  };

  int*   dflag  = (int*)  alloc(256);
  int*   vtab   = (int*)  alloc(NRK * sizeof(int));
  int*   ksrc   = (int*)  alloc((size_t)32 * NKEY * sizeof(int));
  bf16*  buf2   = (bf16*) alloc((size_t)NTOK * FFN_ * 2);   // qkv+qkvp_b -> h1/h2
  float* pooled = (float*)alloc((size_t)256 * C_ * 4);
  float* x2     = (float*)alloc((size_t)NTOK * C_ * 4);
  float* hf     = (float*)alloc((size_t)16 * 40 * 60 * 108 * 4);
  bf16*  wqkv_t = (bf16*) alloc((size_t)1536 * 512 * 2);
  bf16*  wproj_t= (bf16*) alloc((size_t)512 * 512 * 2);
  bf16*  w1_t   = (bf16*) alloc((size_t)2048 * 512 * 2);    // zero-padded 1960->2048
  bf16*  w2_t   = (bf16*) alloc((size_t)512 * FFN_ * 2);
  float* bqkv_f = (float*)alloc(1536 * 4);
  float* bproj_f= (float*)alloc(512 * 4);
  float* bf1_f  = (float*)alloc(FFN_ * 4);
  float* bf2_f  = (float*)alloc(512 * 4);

  bf16* buf1 = (bf16*)d_out;   // xn -> ao -> y scratch (dead before final GEMM)
  bf16* xn = buf1;
  bf16* ao = buf1;
  bf16* y  = buf1;
  bf16* qkv = buf2;
  bf16* h1  = buf2;
  bf16* qkvpb = buf2 + (size_t)NTOK * 1536;   // 257 rows: 256 pooled + 1 zero row

  // detect + prep + zero-row in one launch
  k_init<<<7, 256, 0, stream>>>(g1, dflag, vtab, qkvpb + (size_t)256 * 1536);
  k_ksrc<<<(32 * NKEY) / 256, 256, 0, stream>>>(vtab, ksrc);

  // weight transpose+convert (LDS-tiled), all biases in one launch
  k_wcvt<<<dim3(24, 8), 256, 0, stream>>>(dflag, wqkv, wqkv_t, 512, 1536, 1536);
  k_wcvt<<<dim3(8, 8), 256, 0, stream>>>(dflag, wproj, wproj_t, 512, 512, 512);
  k_wcvt<<<dim3(32, 8), 256, 0, stream>>>(dflag, w1, w1_t, 512, FFN_, 2048);
  k_wcvt<<<dim3(8, 31), 256, 0, stream>>>(dflag, w2, w2_t, FFN_, 512, 512);
  k_bcvt4<<<18, 256, 0, stream>>>(dflag, bqkv, bqkv_f, bproj, bproj_f,
                                  bf1, bf1_f, bf2, bf2_f);

  // LN1
  k_ln<<<NTOK, 256, 0, stream>>>(dflag, 0, x, g1, be1, xn);

  // window pooling
  k_pool<<<512, 256, 0, stream>>>(dflag, xn, wpool, bpool, pooled);

  // qkv = xn @ wqkv + bqkv
  k_gemm_m<0><<<dim3(12, 90), 256, 0, stream>>>(
      nullptr, xn, wqkv_t, bqkv_f, nullptr, qkv, NTOK, 1536, 512);

  // qkv_p = pooled @ wqkv + bqkv -> bf16 rows appended after qkv
  k_gemm_small<<<dim3(6, 32), 256, 0, stream>>>(dflag, pooled, wqkv, bqkv, qkvpb);

  // MFMA flash attention: 256 blocks (1/CU), 12 waves, 192 queries per block
  k_attn_m<<<dim3(32, 2, NH_), 768, 0, stream>>>(qkv, ksrc, ao);

  // x2 = x + ao @ wproj + bproj
  k_gemm_m<1><<<dim3(4, 90), 256, 0, stream>>>(
      dflag, ao, wproj_t, bproj_f, x, x2, NTOK, 512, 512);

  // LN2 -> y
  k_ln<<<NTOK, 256, 0, stream>>>(dflag, 1, x2, g2, be2, y);

  // h1 = y @ w1 + bf1
  k_gemm_m<0><<<dim3(16, 90), 256, 0, stream>>>(
      nullptr, y, w1_t, bf1_f, nullptr, h1, NTOK, FFN_, 512);

  // T2T fold + normalize
  k_fold<<<(16 * 40 * 60 * 108) / 256, 256, 0, stream>>>(h1, hf);

  // T2T unfold + GELU (in place into buf2)
  k_unfold_gelu<<<(NTOK * FFN_) / 256, 256, 0, stream>>>(hf, h1);

  // out = x2 + gelu_h @ w2 + bf2
  k_gemm_m<2><<<dim3(4, 90), 256, 0, stream>>>(
      dflag, h1, w2_t, bf2_f, x2, d_out, NTOK, 512, FFN_);
}